// Round 5
// baseline (151.797 us; speedup 1.0000x reference)
//
#include <hip/hip_runtime.h>
#include <math.h>

// ---------------- constants (replicate reference fp32 op order) -------------
constexpr double dPI     = 3.14159265358979323846;
constexpr double dLAMBDA = 5.32e-7;
constexpr double dK      = 2.0 * dPI / dLAMBDA;
constexpr double dD1     = 0.05;
constexpr double dD2     = 0.05;
constexpr double dFOCAL  = dD1 * dD2 / (dD1 + dD2);      // 0.025

constexpr float C1F         = (float)(dK / (2.0 * dD1)); // input_phase coeff
constexpr float KFF         = (float)dK;
constexpr float TWO_FOCAL_F = (float)(2.0 * dFOCAL);     // 0.05
constexpr float TPF         = (float)(2.0 * dPI);
constexpr float SENSOR_DF   = (float)(4096.0 * 2e-6);    // 8.192e-3
constexpr float ILAM2F      = (float)((1.0 / dLAMBDA) * (1.0 / dLAMBDA));
constexpr float D2F         = (float)dD2;
constexpr float PITCHF      = 2e-6f;
constexpr float SCALE       = 1.0f / 16777216.0f;        // 2^-24 = 1/(4096*4096)
constexpr double INV2PI_D   = 1.0 / (2.0 * dPI);

// tridiag(1,4,1) inverse kernel constants
constexpr float TRI_R = -0.2679491924311227f;            // -2+sqrt(3)
constexpr float TRI_C = 0.2886751345948129f;             // 1/(2*sqrt(3))

// ---------------- packed complex type: maps to v_pk_* fp32 ops --------------
typedef float v2f __attribute__((ext_vector_type(2)));

__device__ __forceinline__ v2f mkv(float a, float b){ v2f r; r.x=a; r.y=b; return r; }
__device__ __forceinline__ v2f vswap(v2f a){ return __builtin_shufflevector(a,a,1,0); }
__device__ __forceinline__ v2f mulpi(v2f a){ v2f s=vswap(a); return mkv(-s.x, s.y); } //  i*a
__device__ __forceinline__ v2f mulmi(v2f a){ v2f s=vswap(a); return mkv(s.x, -s.y); } // -i*a
__device__ __forceinline__ v2f cmul(v2f a, v2f b){
    v2f axx = __builtin_shufflevector(a,a,0,0);
    v2f ayy = __builtin_shufflevector(a,a,1,1);
    v2f bs  = vswap(b);
    v2f t   = mkv(-bs.x, bs.y);            // (-b.y, b.x)
    return axx*b + ayy*t;
}
__device__ __forceinline__ v2f cmulc(v2f a, v2f b){    // a * conj(b)
    v2f axx = __builtin_shufflevector(a,a,0,0);
    v2f ayy = __builtin_shufflevector(a,a,1,1);
    v2f bc  = mkv(b.x, -b.y);
    return axx*bc + ayy*vswap(b);
}

__device__ __forceinline__ int digitrev12(int p){
    int r = __brev((unsigned)p) >> 20;
    return ((r & 0x555) << 1) | ((r >> 1) & 0x555);
}

// ---------------- radix-4 butterflies (DIF fwd / DIT inv) ----------------
__device__ __forceinline__ void bfly_fwd(v2f& A, v2f& B, v2f& C, v2f& D,
                                         v2f w1, v2f w2, v2f w3){
    v2f t0=A+C, t1=A-C, t2=B+D, t3=B-D;
    v2f y0=t0+t2;
    v2f y1=t1+mulmi(t3);
    v2f y2=t0-t2;
    v2f y3=t1+mulpi(t3);
    A=y0; B=cmul(y1,w1); C=cmul(y2,w2); D=cmul(y3,w3);
}
__device__ __forceinline__ void bfly_fwd_nt(v2f& A, v2f& B, v2f& C, v2f& D){
    v2f t0=A+C, t1=A-C, t2=B+D, t3=B-D;
    A=t0+t2;
    v2f y1=t1+mulmi(t3);
    v2f y2=t0-t2;
    v2f y3=t1+mulpi(t3);
    B=y1; C=y2; D=y3;
}
__device__ __forceinline__ void bfly_inv(v2f& A, v2f& B, v2f& C, v2f& D,
                                         v2f w1, v2f w2, v2f w3){
    v2f bb=cmulc(B,w1), cc=cmulc(C,w2), dd=cmulc(D,w3);
    v2f t0=A+cc, t1=A-cc, t2=bb+dd, t3=bb-dd;
    A=t0+t2;
    B=t1+mulpi(t3);
    C=t0-t2;
    D=t1+mulmi(t3);
}
__device__ __forceinline__ void bfly_inv_nt(v2f& A, v2f& B, v2f& C, v2f& D){
    v2f t0=A+C, t1=A-C, t2=B+D, t3=B-D;
    A=t0+t2;
    B=t1+mulpi(t3);
    C=t0-t2;
    D=t1+mulmi(t3);
}

// ---------------- register-fused stage pairs ----------------
// ownership A (strided): r[q] = x[t + 256 q]
// s1 (M=1024,L=4096, table off 0) + s2 (M=256,L=1024, off 1024)
template<bool ZAD>
__device__ __forceinline__ void front_fwd(v2f* r, int t,
        const v2f* __restrict__ tw1, const v2f* __restrict__ tw2,
        const v2f* __restrict__ tw3){
#pragma unroll
    for (int j = 0; j < 4; ++j){
        int m = t + 256*j;
        v2f w1 = tw1[m], w2 = tw2[m], w3 = tw3[m];
        v2f t0, t1, t2, t3;
        if (ZAD){
            v2f Bv = r[j+4], Cv = r[j+8];          // A = D = 0
            t0 = Cv; t1 = -Cv; t2 = Bv; t3 = Bv;
        } else {
            v2f Av=r[j], Bv=r[j+4], Cv=r[j+8], Dv=r[j+12];
            t0=Av+Cv; t1=Av-Cv; t2=Bv+Dv; t3=Bv-Dv;
        }
        v2f y0=t0+t2;
        v2f y1=t1+mulmi(t3);
        v2f y2=t0-t2;
        v2f y3=t1+mulpi(t3);
        r[j]=y0; r[j+4]=cmul(y1,w1); r[j+8]=cmul(y2,w2); r[j+12]=cmul(y3,w3);
    }
    v2f w1 = tw1[1024+t], w2 = tw2[1024+t], w3 = tw3[1024+t];
#pragma unroll
    for (int k = 0; k < 4; ++k)
        bfly_fwd(r[4*k], r[4*k+1], r[4*k+2], r[4*k+3], w1, w2, w3);
}
// ownership C (strided): i5 (M=256) + i6 (M=1024)
__device__ __forceinline__ void back_inv(v2f* r, int t,
        const v2f* __restrict__ tw1, const v2f* __restrict__ tw2,
        const v2f* __restrict__ tw3){
    v2f w1 = tw1[1024+t], w2 = tw2[1024+t], w3 = tw3[1024+t];
#pragma unroll
    for (int k = 0; k < 4; ++k)
        bfly_inv(r[4*k], r[4*k+1], r[4*k+2], r[4*k+3], w1, w2, w3);
#pragma unroll
    for (int j = 0; j < 4; ++j){
        int m = t + 256*j;
        bfly_inv(r[j], r[j+4], r[j+8], r[j+12], tw1[m], tw2[m], tw3[m]);
    }
}
// ownership B (mid): r[g] = x[256*(t>>4) + 16 g + (t&15)]
// s3 (M=64,L=256, off 1280) + s4 (M=16,L=64, off 1344)
__device__ __forceinline__ void mid_fwd(v2f* r, int c,
        const v2f* __restrict__ tw1, const v2f* __restrict__ tw2,
        const v2f* __restrict__ tw3){
#pragma unroll
    for (int h = 0; h < 4; ++h){
        int idx = 1280 + 16*h + c;
        bfly_fwd(r[h], r[h+4], r[h+8], r[h+12], tw1[idx], tw2[idx], tw3[idx]);
    }
    v2f w1 = tw1[1344+c], w2 = tw2[1344+c], w3 = tw3[1344+c];
#pragma unroll
    for (int j = 0; j < 4; ++j)
        bfly_fwd(r[4*j], r[4*j+1], r[4*j+2], r[4*j+3], w1, w2, w3);
}
__device__ __forceinline__ void mid_inv(v2f* r, int c,
        const v2f* __restrict__ tw1, const v2f* __restrict__ tw2,
        const v2f* __restrict__ tw3){
    v2f w1 = tw1[1344+c], w2 = tw2[1344+c], w3 = tw3[1344+c];
#pragma unroll
    for (int j = 0; j < 4; ++j)
        bfly_inv(r[4*j], r[4*j+1], r[4*j+2], r[4*j+3], w1, w2, w3);
#pragma unroll
    for (int h = 0; h < 4; ++h){
        int idx = 1280 + 16*h + c;
        bfly_inv(r[h], r[h+4], r[h+8], r[h+12], tw1[idx], tw2[idx], tw3[idx]);
    }
}
// ownership D (contig): r[g] = x[16 t + g]
// s5 (M=4,L=16, hardcoded) + s6 (M=1,L=4, trivial)
#define C16F 0.9238795325112867f
#define S16F 0.3826834323650898f
#define C8F  0.7071067811865476f
__device__ __forceinline__ void tail_fwd(v2f* r){
    const v2f W1[4] = {mkv(1,0),mkv(C16F,-S16F),mkv(C8F,-C8F),mkv(S16F,-C16F)};
    const v2f W2[4] = {mkv(1,0),mkv(C8F,-C8F),mkv(0,-1),mkv(-C8F,-C8F)};
    const v2f W3[4] = {mkv(1,0),mkv(S16F,-C16F),mkv(-C8F,-C8F),mkv(-C16F,S16F)};
    bfly_fwd_nt(r[0], r[4], r[8], r[12]);
#pragma unroll
    for (int m = 1; m < 4; ++m)
        bfly_fwd(r[m], r[m+4], r[m+8], r[m+12], W1[m], W2[m], W3[m]);
#pragma unroll
    for (int h = 0; h < 4; ++h)
        bfly_fwd_nt(r[4*h], r[4*h+1], r[4*h+2], r[4*h+3]);
}
// i1 (L=4, trivial) + i2 (L=16, conj of hardcoded)
__device__ __forceinline__ void head_inv(v2f* r){
    const v2f W1[4] = {mkv(1,0),mkv(C16F,-S16F),mkv(C8F,-C8F),mkv(S16F,-C16F)};
    const v2f W2[4] = {mkv(1,0),mkv(C8F,-C8F),mkv(0,-1),mkv(-C8F,-C8F)};
    const v2f W3[4] = {mkv(1,0),mkv(S16F,-C16F),mkv(-C8F,-C8F),mkv(-C16F,S16F)};
#pragma unroll
    for (int h = 0; h < 4; ++h)
        bfly_inv_nt(r[4*h], r[4*h+1], r[4*h+2], r[4*h+3]);
    bfly_inv_nt(r[0], r[4], r[8], r[12]);
#pragma unroll
    for (int m = 1; m < 4; ++m)
        bfly_inv(r[m], r[m+4], r[m+8], r[m+12], W1[m], W2[m], W3[m]);
}

// ------- LDS ownership exchanges: fp32 two-phase, 16 KiB buffer -------------
// Same index math as before (bit-identical data movement), but .x and .y move
// in separate phases so the buffer is float[4096] = 16 KiB -> 8 blocks/CU.
// Reads land directly in r[g].x/.y (old value already saved to LDS), so no
// extra VGPRs. Chaining rule preserved: next exchange's write-set == this
// exchange's read-set per thread, so no barrier needed between exchanges.
__device__ __forceinline__ void x_strided_to_mid(v2f* r, float* lds, int t){
    int tsw = t ^ (t >> 4);
    int Bq = (t >> 4) * 256, c = t & 15;
#pragma unroll
    for (int q = 0; q < 16; ++q) lds[256*q + tsw] = r[q].x;
    __syncthreads();
#pragma unroll
    for (int g = 0; g < 16; ++g) r[g].x = lds[Bq + 16*g + (c ^ g)];
    __syncthreads();
#pragma unroll
    for (int q = 0; q < 16; ++q) lds[256*q + tsw] = r[q].y;
    __syncthreads();
#pragma unroll
    for (int g = 0; g < 16; ++g) r[g].y = lds[Bq + 16*g + (c ^ g)];
}
__device__ __forceinline__ void x_mid_to_contig(v2f* r, float* lds, int t){
    int Bq = (t >> 4) * 256, c = t & 15;
    int tl = t & 15, base = 16*t;
#pragma unroll
    for (int g = 0; g < 16; ++g) lds[Bq + 16*g + (c ^ g)] = r[g].x;
    __syncthreads();
#pragma unroll
    for (int g = 0; g < 16; ++g) r[g].x = lds[base + (g ^ tl)];
    __syncthreads();
#pragma unroll
    for (int g = 0; g < 16; ++g) lds[Bq + 16*g + (c ^ g)] = r[g].y;
    __syncthreads();
#pragma unroll
    for (int g = 0; g < 16; ++g) r[g].y = lds[base + (g ^ tl)];
}
__device__ __forceinline__ void x_contig_to_mid(v2f* r, float* lds, int t){
    int tl = t & 15, base = 16*t;
    int Bq = (t >> 4) * 256, c = t & 15;
#pragma unroll
    for (int g = 0; g < 16; ++g) lds[base + (g ^ tl)] = r[g].x;
    __syncthreads();
#pragma unroll
    for (int g = 0; g < 16; ++g) r[g].x = lds[Bq + 16*g + (c ^ g)];
    __syncthreads();
#pragma unroll
    for (int g = 0; g < 16; ++g) lds[base + (g ^ tl)] = r[g].y;
    __syncthreads();
#pragma unroll
    for (int g = 0; g < 16; ++g) r[g].y = lds[Bq + 16*g + (c ^ g)];
}
__device__ __forceinline__ void x_mid_to_strided(v2f* r, float* lds, int t){
    int Bq = (t >> 4) * 256, c = t & 15;
    int tsw = t ^ (t >> 4);
#pragma unroll
    for (int g = 0; g < 16; ++g) lds[Bq + 16*g + (c ^ g)] = r[g].x;
    __syncthreads();
#pragma unroll
    for (int q = 0; q < 16; ++q) r[q].x = lds[256*q + tsw];
    __syncthreads();
#pragma unroll
    for (int g = 0; g < 16; ++g) lds[Bq + 16*g + (c ^ g)] = r[g].y;
    __syncthreads();
#pragma unroll
    for (int q = 0; q < 16; ++q) r[q].y = lds[256*q + tsw];
}

// ---------------- twiddle tables: exact, double-generated -------------------
// layout: [0,1024): M=1024 L=4096 | [1024,1280): M=256 L=1024 |
//         [1280,1344): M=64 L=256 | [1344,1360): M=16 L=64
__global__ __launch_bounds__(256) void k_twiddle(v2f* __restrict__ tw1,
                                                 v2f* __restrict__ tw2,
                                                 v2f* __restrict__ tw3){
    int idx = blockIdx.x * 256 + threadIdx.x;
    if (idx >= 1360) return;
    int m, L;
    if (idx < 1024)      { m = idx;        L = 4096; }
    else if (idx < 1280) { m = idx - 1024; L = 1024; }
    else if (idx < 1344) { m = idx - 1280; L = 256;  }
    else                 { m = idx - 1344; L = 64;   }
    double ang = -2.0 * dPI * (double)m / (double)L;
    double s1, c1, s2, c2v, s3, c3;
    sincos(ang, &s1, &c1);
    sincos(2.0*ang, &s2, &c2v);
    sincos(3.0*ang, &s3, &c3);
    tw1[idx] = mkv((float)c1,  (float)s1);
    tw2[idx] = mkv((float)c2v, (float)s2);
    tw3[idx] = mkv((float)c3,  (float)s3);
}

// ---------------- spline: Y build + parallel analytic tridiag solve ---------
__global__ __launch_bounds__(256) void k_sY(const float* __restrict__ p,
                                            float* __restrict__ Y){
    int t = threadIdx.x;
#pragma unroll
    for (int q = 0; q < 8; ++q){
        int j = t + 256*q;
        Y[j] = (j < 1024) ? p[j >> 1] : 0.0f;   // repeat(param,2) ++ zeros
    }
}
// M = T^{-1} rhs, T = tridiag(1,4,1) size 2046; analytic decay kernel + image terms
__global__ __launch_bounds__(256) void k_sM(const float* __restrict__ Y,
                                            float* __restrict__ Mv){
    __shared__ float sY[328];
    int t = threadIdx.x;
    int B0 = blockIdx.x * 256;
    for (int k = t; k < 324; k += 256){
        int jg = B0 - 32 + k;
        sY[k] = (jg >= 0 && jg < 2048) ? Y[jg] : 0.0f;
    }
    __syncthreads();
    int i = B0 + t;
    if (i >= 2046) return;
    auto rhs = [&](int j) -> float {
        if (j < 0 || j >= 2046) return 0.0f;
        int l = j - B0 + 32;
        return 6.0f * (sY[l+2] - 2.0f*sY[l+1] + sY[l]);
    };
    float x = TRI_C * rhs(i);
    float wd = TRI_C;
    for (int d = 1; d <= 32; ++d){
        wd *= TRI_R;
        x += wd * (rhs(i-d) + rhs(i+d));
    }
    if (i < 48){                       // left image charge
        float cA = 0.0f, wj = TRI_C;
        for (int j = 0; j < 32; ++j){ wj *= TRI_R; cA += wj * rhs(j); }
        float rp = 1.0f;
        for (int k = 0; k <= i; ++k) rp *= TRI_R;    // r^{i+1}
        x -= cA * rp;
    }
    if (i >= 1998){                    // right image charge
        float cB = 0.0f, wj = TRI_C;
        for (int j = 0; j < 32; ++j){ wj *= TRI_R; cB += wj * rhs(2045 - j); }
        float rp = 1.0f;
        for (int k = 0; k < 2046 - i; ++k) rp *= TRI_R;  // r^{2046-i}
        x -= cB * rp;
    }
    Mv[i+1] = x;
    if (i == 0)    Mv[0]    = 0.0f;
    if (i == 2045) Mv[2047] = 0.0f;
}

// ---------------- pass 1: field build + fwd row FFT -------------------------
// output layout: F1[row][c'] with c' = 256 g + t  <->  storage pos p = 16 t + g
__global__ __launch_bounds__(256) void k_pass1(const float* __restrict__ Y,
        const float* __restrict__ Mv,
        const v2f* __restrict__ tw1, const v2f* __restrict__ tw2,
        const v2f* __restrict__ tw3, v2f* __restrict__ F1){
    __shared__ float lds[4096];
    int t = threadIdx.x;
    int row = blockIdx.x;                 // y = 1024 + row
    v2f r[16];
    int y = 1024 + row;
    int iy = row;
    int a = (iy < 1024) ? (1023 - iy) : (iy - 1024);
    float fy = PITCHF * (float)(y - 2048);
    float cy2 = fy * fy;
    float af = (float)a + 0.5f;
#pragma unroll
    for (int q = 4; q < 12; ++q){
        int x = t + 256*q;                // in [1024, 3072)
        int ix = x - 1024;
        int b = (ix < 1024) ? (1023 - ix) : (ix - 1024);
        float bf = (float)b + 0.5f;
        float rq = sqrtf(af*af + bf*bf);
        int ind = (int)rq; if (ind > 2046) ind = 2046;
        float tt = rq - (float)ind;
        float y0v = Y[ind], y1v = Y[ind+1];
        float m0 = Mv[ind], m1 = Mv[ind+1];
        float bb = (y1v - y0v) - (2.0f*m0 + m1) / 6.0f;
        float bias = y0v + tt*(bb + tt*(m0/2.0f + tt*(m1-m0)/6.0f));
        float fx = PITCHF * (float)(x - 2048);
        float r2 = fx*fx + cy2;
        float ip = C1F * r2;
        float lp = -((KFF * r2) / TWO_FOCAL_F);
        float sp = ip + lp + bias;
        float ph = fmodf(sp, TPF);
        if (ph < 0.0f) ph += TPF;
        float sn, cs; __sincosf(ph, &sn, &cs);
        r[q] = mkv(cs, sn);
    }
    front_fwd<true>(r, t, tw1, tw2, tw3);
    x_strided_to_mid(r, lds, t);
    mid_fwd(r, t & 15, tw1, tw2, tw3);
    x_mid_to_contig(r, lds, t);
    tail_fwd(r);
    size_t base = (size_t)row * 4096;
#pragma unroll
    for (int g = 0; g < 16; ++g)
        F1[base + 256*g + t] = r[g];      // coalesced per g
}

// ------- tiled complex transpose, float4-vectorized: in[H][W] -> out[W][H] --
// H, W must be even (true for all uses: 2048/4096, 4096/728).
__global__ __launch_bounds__(256) void k_transpose(const v2f* __restrict__ in,
                                                   v2f* __restrict__ out,
                                                   int H, int W){
    __shared__ v2f tile[32][33];
    int bx = blockIdx.x * 32, by = blockIdx.y * 32;
    int tx = threadIdx.x, ty = threadIdx.y;   // (16,16)
#pragma unroll
    for (int k = 0; k < 32; k += 16){
        int rr = by + ty + k, cc = bx + 2*tx;
        if (rr < H && cc < W){
            float4 v = *(const float4*)&in[(size_t)rr * W + cc];
            tile[ty + k][2*tx]     = mkv(v.x, v.y);
            tile[ty + k][2*tx + 1] = mkv(v.z, v.w);
        }
    }
    __syncthreads();
#pragma unroll
    for (int k = 0; k < 32; k += 16){
        int rr = bx + ty + k, cc = by + 2*tx;
        if (rr < W && cc < H){
            v2f a = tile[2*tx][ty + k];
            v2f b = tile[2*tx + 1][ty + k];
            float4 v = make_float4(a.x, a.y, b.x, b.y);
            *(float4*)&out[(size_t)rr * H + cc] = v;
        }
    }
}

// ---------------- pass 2: col fwd FFT + H + col inv FFT, crop ---------------
__global__ __launch_bounds__(256) void k_pass2(const v2f* __restrict__ F1T,
        const v2f* __restrict__ tw1, const v2f* __restrict__ tw2,
        const v2f* __restrict__ tw3, v2f* __restrict__ GT){
    __shared__ float lds[4096];
    int t = threadIdx.x;
    int cp = blockIdx.x;                  // c' column index
    v2f r[16];
    size_t base = (size_t)cp * 2048;
#pragma unroll
    for (int q = 4; q < 12; ++q)
        r[q] = F1T[base + t + 256*(q-4)]; // y = t + 256 q, nonzero half
    front_fwd<true>(r, t, tw1, tw2, tw3);
    x_strided_to_mid(r, lds, t);
    mid_fwd(r, t & 15, tw1, tw2, tw3);
    x_mid_to_contig(r, lds, t);
    tail_fwd(r);
    // ---- H multiply in digit-reversed frequency domain (incl. 1/N^2) ----
    int pcol = ((cp & 255) << 4) | (cp >> 8);
    int kx = digitrev12(pcol);
    int kxs = (kx + 2048) & 4095;
    float fxv = ((float)(kxs + 1) - 2048.0f) / SENSOR_DF;
    float fx2 = fxv * fxv;
    int rt = __brev((unsigned)t) >> 24;
    rt = ((rt & 0x55) << 1) | ((rt >> 1) & 0x55);   // 4-digit base-4 reversal of t
#pragma unroll
    for (int g = 0; g < 16; ++g){
        const int rg = ((g & 3) << 2) | (g >> 2);
        int ky = rg * 256 + rt;                      // digitrev12(16 t + g)
        int kys = (ky + 2048) & 4095;
        float fyv = ((float)(kys + 1) - 2048.0f) / SENSOR_DF;
        float arg = ILAM2F - fx2 - fyv*fyv;
        arg = fmaxf(arg, 0.0f);
        float w1v = sqrtf(arg);
        float Hp = (TPF * w1v) * D2F;                // exact ref fp32 value
        // exact mod-2pi reduction in double, then HW sincos (fast path)
        double fr = (double)Hp * INV2PI_D;
        fr -= floor(fr);
        float ph = (float)fr * TPF;
        float sn, cs; __sincosf(ph, &sn, &cs);
        r[g] = cmul(r[g], mkv(cs * SCALE, sn * SCALE));
    }
    head_inv(r);
    x_contig_to_mid(r, lds, t);
    mid_inv(r, t & 15, tw1, tw2, tw3);
    x_mid_to_strided(r, lds, t);
    back_inv(r, t, tw1, tw2, tw3);
    size_t ob = (size_t)cp * 728;
#pragma unroll
    for (int q = 6; q <= 9; ++q){
        int idx = t + 256*q - 1685;       // crop y in [1685, 2413)
        if (idx >= 0 && idx < 728) GT[ob + idx] = r[q];
    }
}

// ---------------- pass 3: inv row FFT on crop rows, |.|^2 -------------------
__global__ __launch_bounds__(256) void k_pass3(const v2f* __restrict__ G,
        float* __restrict__ out, float* __restrict__ partials,
        const v2f* __restrict__ tw1, const v2f* __restrict__ tw2,
        const v2f* __restrict__ tw3){
    __shared__ float lds[4096];
    int t = threadIdx.x;
    int row = blockIdx.x;
    v2f r[16];
    size_t base = (size_t)row * 4096;
#pragma unroll
    for (int g = 0; g < 16; ++g)
        r[g] = G[base + 256*g + t];       // c' = 256 g + t <-> p = 16 t + g
    head_inv(r);
    x_contig_to_mid(r, lds, t);
    mid_inv(r, t & 15, tw1, tw2, tw3);
    x_mid_to_strided(r, lds, t);
    back_inv(r, t, tw1, tw2, tw3);
    float lsum = 0.0f;
#pragma unroll
    for (int q = 6; q <= 9; ++q){
        int idx = t + 256*q - 1685;
        if (idx >= 0 && idx < 728){
            v2f v = r[q];
            float I = v.x*v.x + v.y*v.y;
            out[(size_t)row * 728 + idx] = I;
            lsum += I;
        }
    }
    __syncthreads();                       // all exchange reads done
    lds[t] = lsum;
    __syncthreads();
    for (int k2 = 128; k2 > 0; k2 >>= 1){
        if (t < k2) lds[t] += lds[t + k2];
        __syncthreads();
    }
    if (t == 0) partials[row] = lds[0];
}

// ---------------- deterministic final reduction + normalize -----------------
__global__ __launch_bounds__(256) void k_reduce(const float* __restrict__ partials,
                                                float* __restrict__ total){
    __shared__ float red[256];
    int t = threadIdx.x;
    float s = 0.0f;
    for (int i = t; i < 728; i += 256) s += partials[i];
    red[t] = s;
    __syncthreads();
    for (int k = 128; k > 0; k >>= 1){
        if (t < k) red[t] += red[t + k];
        __syncthreads();
    }
    if (t == 0) *total = red[0];
}

__global__ __launch_bounds__(256) void k_norm(float* __restrict__ out,
                                              const float* __restrict__ total,
                                              int n){
    int i = blockIdx.x * 256 + threadIdx.x;
    if (i < n) out[i] = out[i] / (*total);
}

// ---------------- launch ----------------
extern "C" void kernel_launch(void* const* d_in, const int* in_sizes, int n_in,
                              void* d_out, int out_size, void* d_ws, size_t ws_size,
                              hipStream_t stream) {
    const float* p   = (const float*)d_in[0];
    float*       out = (float*)d_out;
    char*        ws  = (char*)d_ws;

    float* Y        = (float*)(ws + 0);            // 2048 f
    float* Mv       = (float*)(ws + 8192);         // 2048 f
    float* partials = (float*)(ws + 16384);        // 728 f
    float* total    = (float*)(ws + 20480);
    v2f*   tw1      = (v2f*)(ws + 24576);          // 1360 c
    v2f*   tw2      = (v2f*)(ws + 40960);
    v2f*   tw3      = (v2f*)(ws + 57344);

    const size_t BIG = (size_t)64 * 1024 * 1024;
    v2f* F1  = (v2f*)(ws + (1 << 20));             // [2048][4096]
    v2f* F1T = (v2f*)(ws + (1 << 20) + BIG);       // [4096][2048]
    v2f* GT  = F1;                                  // reuse: [4096][728]
    v2f* G   = F1T;                                 // reuse: [728][4096]

    k_sY<<<1, 256, 0, stream>>>(p, Y);
    k_sM<<<8, 256, 0, stream>>>(Y, Mv);
    k_twiddle<<<6, 256, 0, stream>>>(tw1, tw2, tw3);
    k_pass1<<<2048, 256, 0, stream>>>(Y, Mv, tw1, tw2, tw3, F1);
    k_transpose<<<dim3(128, 64), dim3(16, 16), 0, stream>>>(F1, F1T, 2048, 4096);
    k_pass2<<<4096, 256, 0, stream>>>(F1T, tw1, tw2, tw3, GT);
    k_transpose<<<dim3(23, 128), dim3(16, 16), 0, stream>>>(GT, G, 4096, 728);
    k_pass3<<<728, 256, 0, stream>>>(G, out, partials, tw1, tw2, tw3);
    k_reduce<<<1, 256, 0, stream>>>(partials, total);
    int n = out_size;
    k_norm<<<(n + 255) / 256, 256, 0, stream>>>(out, total, n);
}

// Round 6
// 146.794 us; speedup vs baseline: 1.0341x; 1.0341x over previous
//
#include <hip/hip_runtime.h>
#include <math.h>

// ---------------- constants (replicate reference fp32 op order) -------------
constexpr double dPI     = 3.14159265358979323846;
constexpr double dLAMBDA = 5.32e-7;
constexpr double dK      = 2.0 * dPI / dLAMBDA;
constexpr double dD1     = 0.05;
constexpr double dD2     = 0.05;
constexpr double dFOCAL  = dD1 * dD2 / (dD1 + dD2);      // 0.025

constexpr float C1F         = (float)(dK / (2.0 * dD1)); // input_phase coeff
constexpr float KFF         = (float)dK;
constexpr float TWO_FOCAL_F = (float)(2.0 * dFOCAL);     // 0.05
constexpr float TPF         = (float)(2.0 * dPI);
constexpr float INV_TPF     = (float)(1.0 / (2.0 * dPI));
constexpr float SENSOR_DF   = (float)(4096.0 * 2e-6);    // 8.192e-3
constexpr float ILAM2F      = (float)((1.0 / dLAMBDA) * (1.0 / dLAMBDA));
constexpr float D2F         = (float)dD2;
constexpr float PITCHF      = 2e-6f;
constexpr float SCALE       = 1.0f / 16777216.0f;        // 2^-24 = 1/(4096*4096)
constexpr double INV2PI_D   = 1.0 / (2.0 * dPI);

// tridiag(1,4,1) inverse kernel constants
constexpr float TRI_R = -0.2679491924311227f;            // -2+sqrt(3)
constexpr float TRI_C = 0.2886751345948129f;             // 1/(2*sqrt(3))

// ---------------- packed complex type ----------------
// v2f used for storage + pure complex adds (pk_add); all products use explicit
// component mul/fma (4 ops, input-modifier negation, no shuffles).
typedef float v2f __attribute__((ext_vector_type(2)));

__device__ __forceinline__ v2f mkv(float a, float b){ v2f r; r.x=a; r.y=b; return r; }
__device__ __forceinline__ v2f cmul(v2f a, v2f b){
    float p  = a.y * b.y;
    float re = fmaf(a.x, b.x, -p);
    float q  = a.y * b.x;
    float im = fmaf(a.x, b.y,  q);
    return mkv(re, im);
}
__device__ __forceinline__ v2f cmulc(v2f a, v2f b){    // a * conj(b)
    float p  = a.y * b.y;
    float re = fmaf(a.x, b.x,  p);
    float q  = a.x * b.y;
    float im = fmaf(a.y, b.x, -q);
    return mkv(re, im);
}

__device__ __forceinline__ int digitrev12(int p){
    int r = __brev((unsigned)p) >> 20;
    return ((r & 0x555) << 1) | ((r >> 1) & 0x555);
}

// ---------------- radix-4 butterflies (DIF fwd / DIT inv) ----------------
__device__ __forceinline__ void bfly_fwd(v2f& A, v2f& B, v2f& C, v2f& D,
                                         v2f w1, v2f w2, v2f w3){
    v2f t0=A+C, t1=A-C, t2=B+D, t3=B-D;
    v2f y0=t0+t2;
    v2f y1=mkv(t1.x + t3.y, t1.y - t3.x);   // t1 - i t3
    v2f y2=t0-t2;
    v2f y3=mkv(t1.x - t3.y, t1.y + t3.x);   // t1 + i t3
    A=y0; B=cmul(y1,w1); C=cmul(y2,w2); D=cmul(y3,w3);
}
__device__ __forceinline__ void bfly_fwd_nt(v2f& A, v2f& B, v2f& C, v2f& D){
    v2f t0=A+C, t1=A-C, t2=B+D, t3=B-D;
    A=t0+t2;
    v2f y1=mkv(t1.x + t3.y, t1.y - t3.x);
    v2f y2=t0-t2;
    v2f y3=mkv(t1.x - t3.y, t1.y + t3.x);
    B=y1; C=y2; D=y3;
}
__device__ __forceinline__ void bfly_inv(v2f& A, v2f& B, v2f& C, v2f& D,
                                         v2f w1, v2f w2, v2f w3){
    v2f bb=cmulc(B,w1), cc=cmulc(C,w2), dd=cmulc(D,w3);
    v2f t0=A+cc, t1=A-cc, t2=bb+dd, t3=bb-dd;
    A=t0+t2;
    B=mkv(t1.x - t3.y, t1.y + t3.x);        // t1 + i t3
    C=t0-t2;
    D=mkv(t1.x + t3.y, t1.y - t3.x);        // t1 - i t3
}
__device__ __forceinline__ void bfly_inv_nt(v2f& A, v2f& B, v2f& C, v2f& D){
    v2f t0=A+C, t1=A-C, t2=B+D, t3=B-D;
    A=t0+t2;
    B=mkv(t1.x - t3.y, t1.y + t3.x);
    C=t0-t2;
    D=mkv(t1.x + t3.y, t1.y - t3.x);
}

// ---------------- register-fused stage pairs ----------------
// ownership A (strided): r[q] = x[t + 256 q]
// s1 (M=1024,L=4096, table off 0) + s2 (M=256,L=1024, off 1024)
template<bool ZAD>
__device__ __forceinline__ void front_fwd(v2f* r, int t,
        const v2f* __restrict__ tw1, const v2f* __restrict__ tw2,
        const v2f* __restrict__ tw3){
#pragma unroll
    for (int j = 0; j < 4; ++j){
        int m = t + 256*j;
        v2f w1 = tw1[m], w2 = tw2[m], w3 = tw3[m];
        v2f y0, y1, y2, y3;
        if (ZAD){
            v2f Bv = r[j+4], Cv = r[j+8];          // A = D = 0
            // t0=Cv, t1=-Cv, t2=Bv, t3=Bv
            y0 = Cv + Bv;
            y1 = mkv(-Cv.x + Bv.y, -Cv.y - Bv.x);
            y2 = Cv - Bv;
            y3 = mkv(-Cv.x - Bv.y, -Cv.y + Bv.x);
        } else {
            v2f Av=r[j], Bv=r[j+4], Cv=r[j+8], Dv=r[j+12];
            v2f t0=Av+Cv, t1=Av-Cv, t2=Bv+Dv, t3=Bv-Dv;
            y0=t0+t2;
            y1=mkv(t1.x + t3.y, t1.y - t3.x);
            y2=t0-t2;
            y3=mkv(t1.x - t3.y, t1.y + t3.x);
        }
        r[j]=y0; r[j+4]=cmul(y1,w1); r[j+8]=cmul(y2,w2); r[j+12]=cmul(y3,w3);
    }
    v2f w1 = tw1[1024+t], w2 = tw2[1024+t], w3 = tw3[1024+t];
#pragma unroll
    for (int k = 0; k < 4; ++k)
        bfly_fwd(r[4*k], r[4*k+1], r[4*k+2], r[4*k+3], w1, w2, w3);
}
// ownership C (strided): i5 (M=256) + i6 (M=1024)
__device__ __forceinline__ void back_inv(v2f* r, int t,
        const v2f* __restrict__ tw1, const v2f* __restrict__ tw2,
        const v2f* __restrict__ tw3){
    v2f w1 = tw1[1024+t], w2 = tw2[1024+t], w3 = tw3[1024+t];
#pragma unroll
    for (int k = 0; k < 4; ++k)
        bfly_inv(r[4*k], r[4*k+1], r[4*k+2], r[4*k+3], w1, w2, w3);
#pragma unroll
    for (int j = 0; j < 4; ++j){
        int m = t + 256*j;
        bfly_inv(r[j], r[j+4], r[j+8], r[j+12], tw1[m], tw2[m], tw3[m]);
    }
}
// ownership B (mid): r[g] = x[256*(t>>4) + 16 g + (t&15)]
// s3 (M=64,L=256, off 1280) + s4 (M=16,L=64, off 1344)
__device__ __forceinline__ void mid_fwd(v2f* r, int c,
        const v2f* __restrict__ tw1, const v2f* __restrict__ tw2,
        const v2f* __restrict__ tw3){
#pragma unroll
    for (int h = 0; h < 4; ++h){
        int idx = 1280 + 16*h + c;
        bfly_fwd(r[h], r[h+4], r[h+8], r[h+12], tw1[idx], tw2[idx], tw3[idx]);
    }
    v2f w1 = tw1[1344+c], w2 = tw2[1344+c], w3 = tw3[1344+c];
#pragma unroll
    for (int j = 0; j < 4; ++j)
        bfly_fwd(r[4*j], r[4*j+1], r[4*j+2], r[4*j+3], w1, w2, w3);
}
__device__ __forceinline__ void mid_inv(v2f* r, int c,
        const v2f* __restrict__ tw1, const v2f* __restrict__ tw2,
        const v2f* __restrict__ tw3){
    v2f w1 = tw1[1344+c], w2 = tw2[1344+c], w3 = tw3[1344+c];
#pragma unroll
    for (int j = 0; j < 4; ++j)
        bfly_inv(r[4*j], r[4*j+1], r[4*j+2], r[4*j+3], w1, w2, w3);
#pragma unroll
    for (int h = 0; h < 4; ++h){
        int idx = 1280 + 16*h + c;
        bfly_inv(r[h], r[h+4], r[h+8], r[h+12], tw1[idx], tw2[idx], tw3[idx]);
    }
}
// ownership D (contig): r[g] = x[16 t + g]
// s5 (M=4,L=16, hardcoded) + s6 (M=1,L=4, trivial)
#define C16F 0.9238795325112867f
#define S16F 0.3826834323650898f
#define C8F  0.7071067811865476f
__device__ __forceinline__ void tail_fwd(v2f* r){
    const v2f W1[4] = {mkv(1,0),mkv(C16F,-S16F),mkv(C8F,-C8F),mkv(S16F,-C16F)};
    const v2f W2[4] = {mkv(1,0),mkv(C8F,-C8F),mkv(0,-1),mkv(-C8F,-C8F)};
    const v2f W3[4] = {mkv(1,0),mkv(S16F,-C16F),mkv(-C8F,-C8F),mkv(-C16F,S16F)};
    bfly_fwd_nt(r[0], r[4], r[8], r[12]);
#pragma unroll
    for (int m = 1; m < 4; ++m)
        bfly_fwd(r[m], r[m+4], r[m+8], r[m+12], W1[m], W2[m], W3[m]);
#pragma unroll
    for (int h = 0; h < 4; ++h)
        bfly_fwd_nt(r[4*h], r[4*h+1], r[4*h+2], r[4*h+3]);
}
// i1 (L=4, trivial) + i2 (L=16, conj of hardcoded)
__device__ __forceinline__ void head_inv(v2f* r){
    const v2f W1[4] = {mkv(1,0),mkv(C16F,-S16F),mkv(C8F,-C8F),mkv(S16F,-C16F)};
    const v2f W2[4] = {mkv(1,0),mkv(C8F,-C8F),mkv(0,-1),mkv(-C8F,-C8F)};
    const v2f W3[4] = {mkv(1,0),mkv(S16F,-C16F),mkv(-C8F,-C8F),mkv(-C16F,S16F)};
#pragma unroll
    for (int h = 0; h < 4; ++h)
        bfly_inv_nt(r[4*h], r[4*h+1], r[4*h+2], r[4*h+3]);
    bfly_inv_nt(r[0], r[4], r[8], r[12]);
#pragma unroll
    for (int m = 1; m < 4; ++m)
        bfly_inv(r[m], r[m+4], r[m+8], r[m+12], W1[m], W2[m], W3[m]);
}

// ---------------- LDS ownership exchanges (v2f, XOR-swizzled, 1 barrier) ----
// (round-4 form: 16 KiB-halving experiment regressed — b32 patterns 4x'd bank
//  conflicts and occupancy didn't move, so 32 KiB v2f is the right point)
__device__ __forceinline__ void x_strided_to_mid(v2f* r, v2f* lds, int t){
    int tsw = t ^ (t >> 4);
#pragma unroll
    for (int q = 0; q < 16; ++q) lds[256*q + tsw] = r[q];
    __syncthreads();
    int Bq = (t >> 4) * 256, c = t & 15;
#pragma unroll
    for (int g = 0; g < 16; ++g) r[g] = lds[Bq + 16*g + (c ^ g)];
}
__device__ __forceinline__ void x_mid_to_contig(v2f* r, v2f* lds, int t){
    int Bq = (t >> 4) * 256, c = t & 15;
#pragma unroll
    for (int g = 0; g < 16; ++g) lds[Bq + 16*g + (c ^ g)] = r[g];
    __syncthreads();
    int tl = t & 15, base = 16*t;
#pragma unroll
    for (int g = 0; g < 16; ++g) r[g] = lds[base + (g ^ tl)];
}
__device__ __forceinline__ void x_contig_to_mid(v2f* r, v2f* lds, int t){
    int tl = t & 15, base = 16*t;
#pragma unroll
    for (int g = 0; g < 16; ++g) lds[base + (g ^ tl)] = r[g];
    __syncthreads();
    int Bq = (t >> 4) * 256, c = t & 15;
#pragma unroll
    for (int g = 0; g < 16; ++g) r[g] = lds[Bq + 16*g + (c ^ g)];
}
__device__ __forceinline__ void x_mid_to_strided(v2f* r, v2f* lds, int t){
    int Bq = (t >> 4) * 256, c = t & 15;
#pragma unroll
    for (int g = 0; g < 16; ++g) lds[Bq + 16*g + (c ^ g)] = r[g];
    __syncthreads();
    int tsw = t ^ (t >> 4);
#pragma unroll
    for (int q = 0; q < 16; ++q) r[q] = lds[256*q + tsw];
}

// ---------------- twiddle tables: exact, double-generated -------------------
// layout: [0,1024): M=1024 L=4096 | [1024,1280): M=256 L=1024 |
//         [1280,1344): M=64 L=256 | [1344,1360): M=16 L=64
__global__ __launch_bounds__(256) void k_twiddle(v2f* __restrict__ tw1,
                                                 v2f* __restrict__ tw2,
                                                 v2f* __restrict__ tw3){
    int idx = blockIdx.x * 256 + threadIdx.x;
    if (idx >= 1360) return;
    int m, L;
    if (idx < 1024)      { m = idx;        L = 4096; }
    else if (idx < 1280) { m = idx - 1024; L = 1024; }
    else if (idx < 1344) { m = idx - 1280; L = 256;  }
    else                 { m = idx - 1344; L = 64;   }
    double ang = -2.0 * dPI * (double)m / (double)L;
    double s1, c1, s2, c2v, s3, c3;
    sincos(ang, &s1, &c1);
    sincos(2.0*ang, &s2, &c2v);
    sincos(3.0*ang, &s3, &c3);
    tw1[idx] = mkv((float)c1,  (float)s1);
    tw2[idx] = mkv((float)c2v, (float)s2);
    tw3[idx] = mkv((float)c3,  (float)s3);
}

// ---------------- spline: Y build + parallel analytic tridiag solve ---------
__global__ __launch_bounds__(256) void k_sY(const float* __restrict__ p,
                                            float* __restrict__ Y){
    int t = threadIdx.x;
#pragma unroll
    for (int q = 0; q < 8; ++q){
        int j = t + 256*q;
        Y[j] = (j < 1024) ? p[j >> 1] : 0.0f;   // repeat(param,2) ++ zeros
    }
}
// M = T^{-1} rhs, T = tridiag(1,4,1) size 2046; analytic decay kernel + image terms
__global__ __launch_bounds__(256) void k_sM(const float* __restrict__ Y,
                                            float* __restrict__ Mv){
    __shared__ float sY[328];
    int t = threadIdx.x;
    int B0 = blockIdx.x * 256;
    for (int k = t; k < 324; k += 256){
        int jg = B0 - 32 + k;
        sY[k] = (jg >= 0 && jg < 2048) ? Y[jg] : 0.0f;
    }
    __syncthreads();
    int i = B0 + t;
    if (i >= 2046) return;
    auto rhs = [&](int j) -> float {
        if (j < 0 || j >= 2046) return 0.0f;
        int l = j - B0 + 32;
        return 6.0f * (sY[l+2] - 2.0f*sY[l+1] + sY[l]);
    };
    float x = TRI_C * rhs(i);
    float wd = TRI_C;
    for (int d = 1; d <= 32; ++d){
        wd *= TRI_R;
        x += wd * (rhs(i-d) + rhs(i+d));
    }
    if (i < 48){                       // left image charge
        float cA = 0.0f, wj = TRI_C;
        for (int j = 0; j < 32; ++j){ wj *= TRI_R; cA += wj * rhs(j); }
        float rp = 1.0f;
        for (int k = 0; k <= i; ++k) rp *= TRI_R;    // r^{i+1}
        x -= cA * rp;
    }
    if (i >= 1998){                    // right image charge
        float cB = 0.0f, wj = TRI_C;
        for (int j = 0; j < 32; ++j){ wj *= TRI_R; cB += wj * rhs(2045 - j); }
        float rp = 1.0f;
        for (int k = 0; k < 2046 - i; ++k) rp *= TRI_R;  // r^{2046-i}
        x -= cB * rp;
    }
    Mv[i+1] = x;
    if (i == 0)    Mv[0]    = 0.0f;
    if (i == 2045) Mv[2047] = 0.0f;
}

// ---------------- pass 1: field build + fwd row FFT -------------------------
// output layout: F1[row][c'] with c' = 256 g + t  <->  storage pos p = 16 t + g
__global__ __launch_bounds__(256) void k_pass1(const float* __restrict__ Y,
        const float* __restrict__ Mv,
        const v2f* __restrict__ tw1, const v2f* __restrict__ tw2,
        const v2f* __restrict__ tw3, v2f* __restrict__ F1){
    __shared__ v2f lds[4096];
    int t = threadIdx.x;
    int row = blockIdx.x;                 // y = 1024 + row
    v2f r[16];
    int y = 1024 + row;
    int iy = row;
    int a = (iy < 1024) ? (1023 - iy) : (iy - 1024);
    float fy = PITCHF * (float)(y - 2048);
    float cy2 = fy * fy;
    float af = (float)a + 0.5f;
#pragma unroll
    for (int q = 4; q < 12; ++q){
        int x = t + 256*q;                // in [1024, 3072)
        int ix = x - 1024;
        int b = (ix < 1024) ? (1023 - ix) : (ix - 1024);
        float bf = (float)b + 0.5f;
        float rq = sqrtf(af*af + bf*bf);
        int ind = (int)rq; if (ind > 2046) ind = 2046;
        float tt = rq - (float)ind;
        float y0v = Y[ind], y1v = Y[ind+1];
        float m0 = Mv[ind], m1 = Mv[ind+1];
        float bb = (y1v - y0v) - (2.0f*m0 + m1) / 6.0f;
        float bias = y0v + tt*(bb + tt*(m0/2.0f + tt*(m1-m0)/6.0f));
        float fx = PITCHF * (float)(x - 2048);
        float r2 = fx*fx + cy2;
        float ip = C1F * r2;
        float lp = -((KFF * r2) / TWO_FOCAL_F);
        float sp = ip + lp + bias;
        float ph = sp - TPF * floorf(sp * INV_TPF);   // mod 2pi, cheap form
        float sn, cs; __sincosf(ph, &sn, &cs);
        r[q] = mkv(cs, sn);
    }
    front_fwd<true>(r, t, tw1, tw2, tw3);
    x_strided_to_mid(r, lds, t);
    mid_fwd(r, t & 15, tw1, tw2, tw3);
    x_mid_to_contig(r, lds, t);
    tail_fwd(r);
    size_t base = (size_t)row * 4096;
#pragma unroll
    for (int g = 0; g < 16; ++g)
        F1[base + 256*g + t] = r[g];      // coalesced per g
}

// ------- tiled complex transpose, float4-vectorized: in[H][W] -> out[W][H] --
__global__ __launch_bounds__(256) void k_transpose(const v2f* __restrict__ in,
                                                   v2f* __restrict__ out,
                                                   int H, int W){
    __shared__ v2f tile[32][33];
    int bx = blockIdx.x * 32, by = blockIdx.y * 32;
    int tx = threadIdx.x, ty = threadIdx.y;   // (16,16)
#pragma unroll
    for (int k = 0; k < 32; k += 16){
        int rr = by + ty + k, cc = bx + 2*tx;
        if (rr < H && cc < W){
            float4 v = *(const float4*)&in[(size_t)rr * W + cc];
            tile[ty + k][2*tx]     = mkv(v.x, v.y);
            tile[ty + k][2*tx + 1] = mkv(v.z, v.w);
        }
    }
    __syncthreads();
#pragma unroll
    for (int k = 0; k < 32; k += 16){
        int rr = bx + ty + k, cc = by + 2*tx;
        if (rr < W && cc < H){
            v2f a = tile[2*tx][ty + k];
            v2f b = tile[2*tx + 1][ty + k];
            float4 v = make_float4(a.x, a.y, b.x, b.y);
            *(float4*)&out[(size_t)rr * H + cc] = v;
        }
    }
}

// ---------------- pass 2: col fwd FFT + H + col inv FFT, crop ---------------
__global__ __launch_bounds__(256) void k_pass2(const v2f* __restrict__ F1T,
        const v2f* __restrict__ tw1, const v2f* __restrict__ tw2,
        const v2f* __restrict__ tw3, v2f* __restrict__ GT){
    __shared__ v2f lds[4096];
    int t = threadIdx.x;
    int cp = blockIdx.x;                  // c' column index
    v2f r[16];
    size_t base = (size_t)cp * 2048;
#pragma unroll
    for (int q = 4; q < 12; ++q)
        r[q] = F1T[base + t + 256*(q-4)]; // y = t + 256 q, nonzero half
    front_fwd<true>(r, t, tw1, tw2, tw3);
    x_strided_to_mid(r, lds, t);
    mid_fwd(r, t & 15, tw1, tw2, tw3);
    x_mid_to_contig(r, lds, t);
    tail_fwd(r);
    // ---- H multiply in digit-reversed frequency domain (incl. 1/N^2) ----
    int pcol = ((cp & 255) << 4) | (cp >> 8);
    int kx = digitrev12(pcol);
    int kxs = (kx + 2048) & 4095;
    float fxv = ((float)(kxs + 1) - 2048.0f) / SENSOR_DF;
    float fx2 = fxv * fxv;
    int rt = __brev((unsigned)t) >> 24;
    rt = ((rt & 0x55) << 1) | ((rt >> 1) & 0x55);   // 4-digit base-4 reversal of t
#pragma unroll
    for (int g = 0; g < 16; ++g){
        const int rg = ((g & 3) << 2) | (g >> 2);
        int ky = rg * 256 + rt;                      // digitrev12(16 t + g)
        int kys = (ky + 2048) & 4095;
        float fyv = ((float)(kys + 1) - 2048.0f) / SENSOR_DF;
        float arg = ILAM2F - fx2 - fyv*fyv;
        arg = fmaxf(arg, 0.0f);
        float w1v = sqrtf(arg);
        float Hp = (TPF * w1v) * D2F;                // exact ref fp32 value
        // exact mod-2pi reduction in double, then HW sincos (fast path)
        double fr = (double)Hp * INV2PI_D;
        fr -= floor(fr);
        float ph = (float)fr * TPF;
        float sn, cs; __sincosf(ph, &sn, &cs);
        r[g] = cmul(r[g], mkv(cs * SCALE, sn * SCALE));
    }
    head_inv(r);
    x_contig_to_mid(r, lds, t);
    mid_inv(r, t & 15, tw1, tw2, tw3);
    x_mid_to_strided(r, lds, t);
    back_inv(r, t, tw1, tw2, tw3);
    size_t ob = (size_t)cp * 728;
#pragma unroll
    for (int q = 6; q <= 9; ++q){
        int idx = t + 256*q - 1685;       // crop y in [1685, 2413)
        if (idx >= 0 && idx < 728) GT[ob + idx] = r[q];
    }
}

// ---------------- pass 3: inv row FFT on crop rows, |.|^2 -------------------
__global__ __launch_bounds__(256) void k_pass3(const v2f* __restrict__ G,
        float* __restrict__ out, float* __restrict__ partials,
        const v2f* __restrict__ tw1, const v2f* __restrict__ tw2,
        const v2f* __restrict__ tw3){
    __shared__ v2f lds[4096];
    int t = threadIdx.x;
    int row = blockIdx.x;
    v2f r[16];
    size_t base = (size_t)row * 4096;
#pragma unroll
    for (int g = 0; g < 16; ++g)
        r[g] = G[base + 256*g + t];       // c' = 256 g + t <-> p = 16 t + g
    head_inv(r);
    x_contig_to_mid(r, lds, t);
    mid_inv(r, t & 15, tw1, tw2, tw3);
    x_mid_to_strided(r, lds, t);
    back_inv(r, t, tw1, tw2, tw3);
    float lsum = 0.0f;
#pragma unroll
    for (int q = 6; q <= 9; ++q){
        int idx = t + 256*q - 1685;
        if (idx >= 0 && idx < 728){
            v2f v = r[q];
            float I = v.x*v.x + v.y*v.y;
            out[(size_t)row * 728 + idx] = I;
            lsum += I;
        }
    }
    __syncthreads();                       // done reading lds as v2f
    float* red = (float*)lds;
    red[t] = lsum;
    __syncthreads();
    for (int k2 = 128; k2 > 0; k2 >>= 1){
        if (t < k2) red[t] += red[t + k2];
        __syncthreads();
    }
    if (t == 0) partials[row] = red[0];
}

// ---------------- deterministic final reduction + normalize -----------------
__global__ __launch_bounds__(256) void k_reduce(const float* __restrict__ partials,
                                                float* __restrict__ total){
    __shared__ float red[256];
    int t = threadIdx.x;
    float s = 0.0f;
    for (int i = t; i < 728; i += 256) s += partials[i];
    red[t] = s;
    __syncthreads();
    for (int k = 128; k > 0; k >>= 1){
        if (t < k) red[t] += red[t + k];
        __syncthreads();
    }
    if (t == 0) *total = red[0];
}

__global__ __launch_bounds__(256) void k_norm(float* __restrict__ out,
                                              const float* __restrict__ total,
                                              int n){
    int i = blockIdx.x * 256 + threadIdx.x;
    if (i < n) out[i] = out[i] / (*total);
}

// ---------------- launch ----------------
extern "C" void kernel_launch(void* const* d_in, const int* in_sizes, int n_in,
                              void* d_out, int out_size, void* d_ws, size_t ws_size,
                              hipStream_t stream) {
    const float* p   = (const float*)d_in[0];
    float*       out = (float*)d_out;
    char*        ws  = (char*)d_ws;

    float* Y        = (float*)(ws + 0);            // 2048 f
    float* Mv       = (float*)(ws + 8192);         // 2048 f
    float* partials = (float*)(ws + 16384);        // 728 f
    float* total    = (float*)(ws + 20480);
    v2f*   tw1      = (v2f*)(ws + 24576);          // 1360 c
    v2f*   tw2      = (v2f*)(ws + 40960);
    v2f*   tw3      = (v2f*)(ws + 57344);

    const size_t BIG = (size_t)64 * 1024 * 1024;
    v2f* F1  = (v2f*)(ws + (1 << 20));             // [2048][4096]
    v2f* F1T = (v2f*)(ws + (1 << 20) + BIG);       // [4096][2048]
    v2f* GT  = F1;                                  // reuse: [4096][728]
    v2f* G   = F1T;                                 // reuse: [728][4096]

    k_sY<<<1, 256, 0, stream>>>(p, Y);
    k_sM<<<8, 256, 0, stream>>>(Y, Mv);
    k_twiddle<<<6, 256, 0, stream>>>(tw1, tw2, tw3);
    k_pass1<<<2048, 256, 0, stream>>>(Y, Mv, tw1, tw2, tw3, F1);
    k_transpose<<<dim3(128, 64), dim3(16, 16), 0, stream>>>(F1, F1T, 2048, 4096);
    k_pass2<<<4096, 256, 0, stream>>>(F1T, tw1, tw2, tw3, GT);
    k_transpose<<<dim3(23, 128), dim3(16, 16), 0, stream>>>(GT, G, 4096, 728);
    k_pass3<<<728, 256, 0, stream>>>(G, out, partials, tw1, tw2, tw3);
    k_reduce<<<1, 256, 0, stream>>>(partials, total);
    int n = out_size;
    k_norm<<<(n + 255) / 256, 256, 0, stream>>>(out, total, n);
}

// Round 7
// 146.634 us; speedup vs baseline: 1.0352x; 1.0011x over previous
//
#include <hip/hip_runtime.h>
#include <math.h>

// ---------------- constants (replicate reference fp32 op order) -------------
constexpr double dPI     = 3.14159265358979323846;
constexpr double dLAMBDA = 5.32e-7;
constexpr double dK      = 2.0 * dPI / dLAMBDA;
constexpr double dD1     = 0.05;
constexpr double dD2     = 0.05;
constexpr double dFOCAL  = dD1 * dD2 / (dD1 + dD2);      // 0.025

constexpr float C1F         = (float)(dK / (2.0 * dD1)); // input_phase coeff
constexpr float KFF         = (float)dK;
constexpr float TWO_FOCAL_F = (float)(2.0 * dFOCAL);     // 0.05
constexpr float TPF         = (float)(2.0 * dPI);
constexpr float INV_TPF     = (float)(1.0 / (2.0 * dPI));
constexpr float TPH         = (float)(2.0 * dPI);                     // 2pi hi
constexpr float TPL         = (float)(2.0 * dPI - (double)TPH);       // 2pi lo
constexpr float SENSOR_DF   = (float)(4096.0 * 2e-6);    // 8.192e-3
constexpr float ILAM2F      = (float)((1.0 / dLAMBDA) * (1.0 / dLAMBDA));
constexpr float D2F         = (float)dD2;
constexpr float PITCHF      = 2e-6f;
constexpr float SCALE       = 1.0f / 16777216.0f;        // 2^-24 = 1/(4096*4096)

// tridiag(1,4,1) inverse kernel constants
constexpr float TRI_R = -0.2679491924311227f;            // -2+sqrt(3)
constexpr float TRI_C = 0.2886751345948129f;             // 1/(2*sqrt(3))

// ---------------- packed complex type ----------------
typedef float v2f __attribute__((ext_vector_type(2)));

__device__ __forceinline__ v2f mkv(float a, float b){ v2f r; r.x=a; r.y=b; return r; }
__device__ __forceinline__ v2f cmul(v2f a, v2f b){
    float p  = a.y * b.y;
    float re = fmaf(a.x, b.x, -p);
    float q  = a.y * b.x;
    float im = fmaf(a.x, b.y,  q);
    return mkv(re, im);
}
__device__ __forceinline__ v2f cmulc(v2f a, v2f b){    // a * conj(b)
    float p  = a.y * b.y;
    float re = fmaf(a.x, b.x,  p);
    float q  = a.x * b.y;
    float im = fmaf(a.y, b.x, -q);
    return mkv(re, im);
}

// twiddle from revolutions (HW v_sin/v_cos take revs: D = sin(2*pi*S))
// all angles are dyadic fractions -m/L -> exact fp32 inputs, |mrev| < 1
__device__ __forceinline__ v2f twid(float mrev){
    return mkv(__builtin_amdgcn_cosf(mrev), __builtin_amdgcn_sinf(mrev));
}

__device__ __forceinline__ int digitrev12(int p){
    int r = __brev((unsigned)p) >> 20;
    return ((r & 0x555) << 1) | ((r >> 1) & 0x555);
}

// ---------------- radix-4 butterflies (DIF fwd / DIT inv) ----------------
__device__ __forceinline__ void bfly_fwd(v2f& A, v2f& B, v2f& C, v2f& D,
                                         v2f w1, v2f w2, v2f w3){
    v2f t0=A+C, t1=A-C, t2=B+D, t3=B-D;
    v2f y0=t0+t2;
    v2f y1=mkv(t1.x + t3.y, t1.y - t3.x);   // t1 - i t3
    v2f y2=t0-t2;
    v2f y3=mkv(t1.x - t3.y, t1.y + t3.x);   // t1 + i t3
    A=y0; B=cmul(y1,w1); C=cmul(y2,w2); D=cmul(y3,w3);
}
__device__ __forceinline__ void bfly_fwd_nt(v2f& A, v2f& B, v2f& C, v2f& D){
    v2f t0=A+C, t1=A-C, t2=B+D, t3=B-D;
    A=t0+t2;
    v2f y1=mkv(t1.x + t3.y, t1.y - t3.x);
    v2f y2=t0-t2;
    v2f y3=mkv(t1.x - t3.y, t1.y + t3.x);
    B=y1; C=y2; D=y3;
}
__device__ __forceinline__ void bfly_inv(v2f& A, v2f& B, v2f& C, v2f& D,
                                         v2f w1, v2f w2, v2f w3){
    v2f bb=cmulc(B,w1), cc=cmulc(C,w2), dd=cmulc(D,w3);
    v2f t0=A+cc, t1=A-cc, t2=bb+dd, t3=bb-dd;
    A=t0+t2;
    B=mkv(t1.x - t3.y, t1.y + t3.x);        // t1 + i t3
    C=t0-t2;
    D=mkv(t1.x + t3.y, t1.y - t3.x);        // t1 - i t3
}
__device__ __forceinline__ void bfly_inv_nt(v2f& A, v2f& B, v2f& C, v2f& D){
    v2f t0=A+C, t1=A-C, t2=B+D, t3=B-D;
    A=t0+t2;
    B=mkv(t1.x - t3.y, t1.y + t3.x);
    C=t0-t2;
    D=mkv(t1.x + t3.y, t1.y - t3.x);
}

// ---------------- register-fused stage pairs (on-the-fly twiddles) ----------
// ownership A (strided): r[q] = x[t + 256 q]
// s1 (M=1024,L=4096) + s2 (M=256,L=1024)
template<bool ZAD>
__device__ __forceinline__ void front_fwd(v2f* r, int t){
#pragma unroll
    for (int j = 0; j < 4; ++j){
        float mr = (float)(t + 256*j) * (-1.0f/4096.0f);
        v2f w1 = twid(mr), w2 = cmul(w1,w1), w3 = cmul(w2,w1);
        v2f y0, y1, y2, y3;
        if (ZAD){
            v2f Bv = r[j+4], Cv = r[j+8];          // A = D = 0
            y0 = Cv + Bv;
            y1 = mkv(-Cv.x + Bv.y, -Cv.y - Bv.x);
            y2 = Cv - Bv;
            y3 = mkv(-Cv.x - Bv.y, -Cv.y + Bv.x);
        } else {
            v2f Av=r[j], Bv=r[j+4], Cv=r[j+8], Dv=r[j+12];
            v2f t0=Av+Cv, t1=Av-Cv, t2=Bv+Dv, t3=Bv-Dv;
            y0=t0+t2;
            y1=mkv(t1.x + t3.y, t1.y - t3.x);
            y2=t0-t2;
            y3=mkv(t1.x - t3.y, t1.y + t3.x);
        }
        r[j]=y0; r[j+4]=cmul(y1,w1); r[j+8]=cmul(y2,w2); r[j+12]=cmul(y3,w3);
    }
    float mr2 = (float)t * (-1.0f/1024.0f);
    v2f w1 = twid(mr2), w2 = cmul(w1,w1), w3 = cmul(w2,w1);
#pragma unroll
    for (int k = 0; k < 4; ++k)
        bfly_fwd(r[4*k], r[4*k+1], r[4*k+2], r[4*k+3], w1, w2, w3);
}
// ownership C (strided): i5 (M=256) + i6 (M=1024)
__device__ __forceinline__ void back_inv(v2f* r, int t){
    float mr2 = (float)t * (-1.0f/1024.0f);
    v2f w1 = twid(mr2), w2 = cmul(w1,w1), w3 = cmul(w2,w1);
#pragma unroll
    for (int k = 0; k < 4; ++k)
        bfly_inv(r[4*k], r[4*k+1], r[4*k+2], r[4*k+3], w1, w2, w3);
#pragma unroll
    for (int j = 0; j < 4; ++j){
        float mr = (float)(t + 256*j) * (-1.0f/4096.0f);
        v2f u1 = twid(mr), u2 = cmul(u1,u1), u3 = cmul(u2,u1);
        bfly_inv(r[j], r[j+4], r[j+8], r[j+12], u1, u2, u3);
    }
}
// ownership B (mid): r[g] = x[256*(t>>4) + 16 g + (t&15)]
// s3 (M=64,L=256) + s4 (M=16,L=64)
__device__ __forceinline__ void mid_fwd(v2f* r, int c){
#pragma unroll
    for (int h = 0; h < 4; ++h){
        float mr = (float)(16*h + c) * (-1.0f/256.0f);
        v2f u1 = twid(mr), u2 = cmul(u1,u1), u3 = cmul(u2,u1);
        bfly_fwd(r[h], r[h+4], r[h+8], r[h+12], u1, u2, u3);
    }
    float mr2 = (float)c * (-1.0f/64.0f);
    v2f w1 = twid(mr2), w2 = cmul(w1,w1), w3 = cmul(w2,w1);
#pragma unroll
    for (int j = 0; j < 4; ++j)
        bfly_fwd(r[4*j], r[4*j+1], r[4*j+2], r[4*j+3], w1, w2, w3);
}
__device__ __forceinline__ void mid_inv(v2f* r, int c){
    float mr2 = (float)c * (-1.0f/64.0f);
    v2f w1 = twid(mr2), w2 = cmul(w1,w1), w3 = cmul(w2,w1);
#pragma unroll
    for (int j = 0; j < 4; ++j)
        bfly_inv(r[4*j], r[4*j+1], r[4*j+2], r[4*j+3], w1, w2, w3);
#pragma unroll
    for (int h = 0; h < 4; ++h){
        float mr = (float)(16*h + c) * (-1.0f/256.0f);
        v2f u1 = twid(mr), u2 = cmul(u1,u1), u3 = cmul(u2,u1);
        bfly_inv(r[h], r[h+4], r[h+8], r[h+12], u1, u2, u3);
    }
}
// ownership D (contig): r[g] = x[16 t + g]
// s5 (M=4,L=16, hardcoded) + s6 (M=1,L=4, trivial)
#define C16F 0.9238795325112867f
#define S16F 0.3826834323650898f
#define C8F  0.7071067811865476f
__device__ __forceinline__ void tail_fwd(v2f* r){
    const v2f W1[4] = {mkv(1,0),mkv(C16F,-S16F),mkv(C8F,-C8F),mkv(S16F,-C16F)};
    const v2f W2[4] = {mkv(1,0),mkv(C8F,-C8F),mkv(0,-1),mkv(-C8F,-C8F)};
    const v2f W3[4] = {mkv(1,0),mkv(S16F,-C16F),mkv(-C8F,-C8F),mkv(-C16F,S16F)};
    bfly_fwd_nt(r[0], r[4], r[8], r[12]);
#pragma unroll
    for (int m = 1; m < 4; ++m)
        bfly_fwd(r[m], r[m+4], r[m+8], r[m+12], W1[m], W2[m], W3[m]);
#pragma unroll
    for (int h = 0; h < 4; ++h)
        bfly_fwd_nt(r[4*h], r[4*h+1], r[4*h+2], r[4*h+3]);
}
// i1 (L=4, trivial) + i2 (L=16, conj of hardcoded)
__device__ __forceinline__ void head_inv(v2f* r){
    const v2f W1[4] = {mkv(1,0),mkv(C16F,-S16F),mkv(C8F,-C8F),mkv(S16F,-C16F)};
    const v2f W2[4] = {mkv(1,0),mkv(C8F,-C8F),mkv(0,-1),mkv(-C8F,-C8F)};
    const v2f W3[4] = {mkv(1,0),mkv(S16F,-C16F),mkv(-C8F,-C8F),mkv(-C16F,S16F)};
#pragma unroll
    for (int h = 0; h < 4; ++h)
        bfly_inv_nt(r[4*h], r[4*h+1], r[4*h+2], r[4*h+3]);
    bfly_inv_nt(r[0], r[4], r[8], r[12]);
#pragma unroll
    for (int m = 1; m < 4; ++m)
        bfly_inv(r[m], r[m+4], r[m+8], r[m+12], W1[m], W2[m], W3[m]);
}

// ---------------- LDS ownership exchanges (v2f, XOR-swizzled, 1 barrier) ----
__device__ __forceinline__ void x_strided_to_mid(v2f* r, v2f* lds, int t){
    int tsw = t ^ (t >> 4);
#pragma unroll
    for (int q = 0; q < 16; ++q) lds[256*q + tsw] = r[q];
    __syncthreads();
    int Bq = (t >> 4) * 256, c = t & 15;
#pragma unroll
    for (int g = 0; g < 16; ++g) r[g] = lds[Bq + 16*g + (c ^ g)];
}
__device__ __forceinline__ void x_mid_to_contig(v2f* r, v2f* lds, int t){
    int Bq = (t >> 4) * 256, c = t & 15;
#pragma unroll
    for (int g = 0; g < 16; ++g) lds[Bq + 16*g + (c ^ g)] = r[g];
    __syncthreads();
    int tl = t & 15, base = 16*t;
#pragma unroll
    for (int g = 0; g < 16; ++g) r[g] = lds[base + (g ^ tl)];
}
__device__ __forceinline__ void x_contig_to_mid(v2f* r, v2f* lds, int t){
    int tl = t & 15, base = 16*t;
#pragma unroll
    for (int g = 0; g < 16; ++g) lds[base + (g ^ tl)] = r[g];
    __syncthreads();
    int Bq = (t >> 4) * 256, c = t & 15;
#pragma unroll
    for (int g = 0; g < 16; ++g) r[g] = lds[Bq + 16*g + (c ^ g)];
}
__device__ __forceinline__ void x_mid_to_strided(v2f* r, v2f* lds, int t){
    int Bq = (t >> 4) * 256, c = t & 15;
#pragma unroll
    for (int g = 0; g < 16; ++g) lds[Bq + 16*g + (c ^ g)] = r[g];
    __syncthreads();
    int tsw = t ^ (t >> 4);
#pragma unroll
    for (int q = 0; q < 16; ++q) r[q] = lds[256*q + tsw];
}

// ---------------- spline: Y build + parallel analytic tridiag solve ---------
__global__ __launch_bounds__(256) void k_sY(const float* __restrict__ p,
                                            float* __restrict__ Y){
    int t = threadIdx.x;
#pragma unroll
    for (int q = 0; q < 8; ++q){
        int j = t + 256*q;
        Y[j] = (j < 1024) ? p[j >> 1] : 0.0f;   // repeat(param,2) ++ zeros
    }
}
// M = T^{-1} rhs, T = tridiag(1,4,1) size 2046; analytic decay kernel + image terms
__global__ __launch_bounds__(256) void k_sM(const float* __restrict__ Y,
                                            float* __restrict__ Mv){
    __shared__ float sY[328];
    int t = threadIdx.x;
    int B0 = blockIdx.x * 256;
    for (int k = t; k < 324; k += 256){
        int jg = B0 - 32 + k;
        sY[k] = (jg >= 0 && jg < 2048) ? Y[jg] : 0.0f;
    }
    __syncthreads();
    int i = B0 + t;
    if (i >= 2046) return;
    auto rhs = [&](int j) -> float {
        if (j < 0 || j >= 2046) return 0.0f;
        int l = j - B0 + 32;
        return 6.0f * (sY[l+2] - 2.0f*sY[l+1] + sY[l]);
    };
    float x = TRI_C * rhs(i);
    float wd = TRI_C;
    for (int d = 1; d <= 32; ++d){
        wd *= TRI_R;
        x += wd * (rhs(i-d) + rhs(i+d));
    }
    if (i < 48){                       // left image charge
        float cA = 0.0f, wj = TRI_C;
        for (int j = 0; j < 32; ++j){ wj *= TRI_R; cA += wj * rhs(j); }
        float rp = 1.0f;
        for (int k = 0; k <= i; ++k) rp *= TRI_R;    // r^{i+1}
        x -= cA * rp;
    }
    if (i >= 1998){                    // right image charge
        float cB = 0.0f, wj = TRI_C;
        for (int j = 0; j < 32; ++j){ wj *= TRI_R; cB += wj * rhs(2045 - j); }
        float rp = 1.0f;
        for (int k = 0; k < 2046 - i; ++k) rp *= TRI_R;  // r^{2046-i}
        x -= cB * rp;
    }
    Mv[i+1] = x;
    if (i == 0)    Mv[0]    = 0.0f;
    if (i == 2045) Mv[2047] = 0.0f;
}

// ---------------- pass 1: field build + fwd row FFT -------------------------
// output layout: F1[row][c'] with c' = 256 g + t  <->  storage pos p = 16 t + g
__global__ __launch_bounds__(256) void k_pass1(const float* __restrict__ Y,
        const float* __restrict__ Mv, v2f* __restrict__ F1){
    __shared__ v2f lds[4096];
    int t = threadIdx.x;
    int row = blockIdx.x;                 // y = 1024 + row
    v2f r[16];
    int y = 1024 + row;
    int iy = row;
    int a = (iy < 1024) ? (1023 - iy) : (iy - 1024);
    float fy = PITCHF * (float)(y - 2048);
    float cy2 = fy * fy;
    float af = (float)a + 0.5f;
#pragma unroll
    for (int q = 4; q < 12; ++q){
        int x = t + 256*q;                // in [1024, 3072)
        int ix = x - 1024;
        int b = (ix < 1024) ? (1023 - ix) : (ix - 1024);
        float bf = (float)b + 0.5f;
        float rq = sqrtf(af*af + bf*bf);
        int ind = (int)rq; if (ind > 2046) ind = 2046;
        float tt = rq - (float)ind;
        float y0v = Y[ind], y1v = Y[ind+1];
        float m0 = Mv[ind], m1 = Mv[ind+1];
        float bb = (y1v - y0v) - (2.0f*m0 + m1) / 6.0f;
        float bias = y0v + tt*(bb + tt*(m0/2.0f + tt*(m1-m0)/6.0f));
        float fx = PITCHF * (float)(x - 2048);
        float r2 = fx*fx + cy2;
        float ip = C1F * r2;
        float lp = -((KFF * r2) / TWO_FOCAL_F);
        float sp = ip + lp + bias;
        float fv = sp * INV_TPF;                     // phase in revolutions
        float fr = fv - floorf(fv);                  // [0,1)
        float sn = __builtin_amdgcn_sinf(fr);
        float cs = __builtin_amdgcn_cosf(fr);
        r[q] = mkv(cs, sn);
    }
    front_fwd<true>(r, t);
    x_strided_to_mid(r, lds, t);
    mid_fwd(r, t & 15);
    x_mid_to_contig(r, lds, t);
    tail_fwd(r);
    size_t base = (size_t)row * 4096;
#pragma unroll
    for (int g = 0; g < 16; ++g)
        F1[base + 256*g + t] = r[g];      // coalesced per g
}

// ------- tiled complex transpose, float4-vectorized: in[H][W] -> out[W][H] --
__global__ __launch_bounds__(256) void k_transpose(const v2f* __restrict__ in,
                                                   v2f* __restrict__ out,
                                                   int H, int W){
    __shared__ v2f tile[32][33];
    int bx = blockIdx.x * 32, by = blockIdx.y * 32;
    int tx = threadIdx.x, ty = threadIdx.y;   // (16,16)
#pragma unroll
    for (int k = 0; k < 32; k += 16){
        int rr = by + ty + k, cc = bx + 2*tx;
        if (rr < H && cc < W){
            float4 v = *(const float4*)&in[(size_t)rr * W + cc];
            tile[ty + k][2*tx]     = mkv(v.x, v.y);
            tile[ty + k][2*tx + 1] = mkv(v.z, v.w);
        }
    }
    __syncthreads();
#pragma unroll
    for (int k = 0; k < 32; k += 16){
        int rr = bx + ty + k, cc = by + 2*tx;
        if (rr < W && cc < H){
            v2f a = tile[2*tx][ty + k];
            v2f b = tile[2*tx + 1][ty + k];
            float4 v = make_float4(a.x, a.y, b.x, b.y);
            *(float4*)&out[(size_t)rr * H + cc] = v;
        }
    }
}

// ---------------- pass 2: col fwd FFT + H + col inv FFT, crop ---------------
__global__ __launch_bounds__(256) void k_pass2(const v2f* __restrict__ F1T,
                                               v2f* __restrict__ GT){
    __shared__ v2f lds[4096];
    int t = threadIdx.x;
    int cp = blockIdx.x;                  // c' column index
    v2f r[16];
    size_t base = (size_t)cp * 2048;
#pragma unroll
    for (int q = 4; q < 12; ++q)
        r[q] = F1T[base + t + 256*(q-4)]; // y = t + 256 q, nonzero half
    front_fwd<true>(r, t);
    x_strided_to_mid(r, lds, t);
    mid_fwd(r, t & 15);
    x_mid_to_contig(r, lds, t);
    tail_fwd(r);
    // ---- H multiply in digit-reversed frequency domain (incl. 1/N^2) ----
    int pcol = ((cp & 255) << 4) | (cp >> 8);
    int kx = digitrev12(pcol);
    int kxs = (kx + 2048) & 4095;
    float fxv = ((float)(kxs + 1) - 2048.0f) / SENSOR_DF;
    float fx2 = fxv * fxv;
    int rt = __brev((unsigned)t) >> 24;
    rt = ((rt & 0x55) << 1) | ((rt >> 1) & 0x55);   // 4-digit base-4 reversal of t
#pragma unroll
    for (int g = 0; g < 16; ++g){
        const int rg = ((g & 3) << 2) | (g >> 2);
        int ky = rg * 256 + rt;                      // digitrev12(16 t + g)
        int kys = (ky + 2048) & 4095;
        float fyv = ((float)(kys + 1) - 2048.0f) / SENSOR_DF;
        float arg = ILAM2F - fx2 - fyv*fyv;
        arg = fmaxf(arg, 0.0f);
        float w1v = sqrtf(arg);
        float Hp = (TPF * w1v) * D2F;                // exact ref fp32 value
        // fp32 Cody-Waite mod-2pi (error ~1e-7 rad), then HW trig on revs
        float v  = Hp * INV_TPF;
        float nn = rintf(v);
        float rr = fmaf(nn, -TPH, Hp);
        rr       = fmaf(nn, -TPL, rr);
        float rev = rr * INV_TPF;                    // in [-0.5, 0.5]
        float sn = __builtin_amdgcn_sinf(rev);
        float cs = __builtin_amdgcn_cosf(rev);
        r[g] = cmul(r[g], mkv(cs * SCALE, sn * SCALE));
    }
    head_inv(r);
    x_contig_to_mid(r, lds, t);
    mid_inv(r, t & 15);
    x_mid_to_strided(r, lds, t);
    back_inv(r, t);
    size_t ob = (size_t)cp * 728;
#pragma unroll
    for (int q = 6; q <= 9; ++q){
        int idx = t + 256*q - 1685;       // crop y in [1685, 2413)
        if (idx >= 0 && idx < 728) GT[ob + idx] = r[q];
    }
}

// ---------------- pass 3: inv row FFT on crop rows, |.|^2 -------------------
__global__ __launch_bounds__(256) void k_pass3(const v2f* __restrict__ G,
        float* __restrict__ out, float* __restrict__ partials){
    __shared__ v2f lds[4096];
    int t = threadIdx.x;
    int row = blockIdx.x;
    v2f r[16];
    size_t base = (size_t)row * 4096;
#pragma unroll
    for (int g = 0; g < 16; ++g)
        r[g] = G[base + 256*g + t];       // c' = 256 g + t <-> p = 16 t + g
    head_inv(r);
    x_contig_to_mid(r, lds, t);
    mid_inv(r, t & 15);
    x_mid_to_strided(r, lds, t);
    back_inv(r, t);
    float lsum = 0.0f;
#pragma unroll
    for (int q = 6; q <= 9; ++q){
        int idx = t + 256*q - 1685;
        if (idx >= 0 && idx < 728){
            v2f v = r[q];
            float I = v.x*v.x + v.y*v.y;
            out[(size_t)row * 728 + idx] = I;
            lsum += I;
        }
    }
    __syncthreads();                       // done reading lds as v2f
    float* red = (float*)lds;
    red[t] = lsum;
    __syncthreads();
    for (int k2 = 128; k2 > 0; k2 >>= 1){
        if (t < k2) red[t] += red[t + k2];
        __syncthreads();
    }
    if (t == 0) partials[row] = red[0];
}

// ---------------- deterministic final reduction + normalize -----------------
__global__ __launch_bounds__(256) void k_reduce(const float* __restrict__ partials,
                                                float* __restrict__ total){
    __shared__ float red[256];
    int t = threadIdx.x;
    float s = 0.0f;
    for (int i = t; i < 728; i += 256) s += partials[i];
    red[t] = s;
    __syncthreads();
    for (int k = 128; k > 0; k >>= 1){
        if (t < k) red[t] += red[t + k];
        __syncthreads();
    }
    if (t == 0) *total = red[0];
}

__global__ __launch_bounds__(256) void k_norm(float* __restrict__ out,
                                              const float* __restrict__ total,
                                              int n){
    int i = blockIdx.x * 256 + threadIdx.x;
    if (i < n) out[i] = out[i] / (*total);
}

// ---------------- launch ----------------
extern "C" void kernel_launch(void* const* d_in, const int* in_sizes, int n_in,
                              void* d_out, int out_size, void* d_ws, size_t ws_size,
                              hipStream_t stream) {
    const float* p   = (const float*)d_in[0];
    float*       out = (float*)d_out;
    char*        ws  = (char*)d_ws;

    float* Y        = (float*)(ws + 0);            // 2048 f
    float* Mv       = (float*)(ws + 8192);         // 2048 f
    float* partials = (float*)(ws + 16384);        // 728 f
    float* total    = (float*)(ws + 20480);

    const size_t BIG = (size_t)64 * 1024 * 1024;
    v2f* F1  = (v2f*)(ws + (1 << 20));             // [2048][4096]
    v2f* F1T = (v2f*)(ws + (1 << 20) + BIG);       // [4096][2048]
    v2f* GT  = F1;                                  // reuse: [4096][728]
    v2f* G   = F1T;                                 // reuse: [728][4096]

    k_sY<<<1, 256, 0, stream>>>(p, Y);
    k_sM<<<8, 256, 0, stream>>>(Y, Mv);
    k_pass1<<<2048, 256, 0, stream>>>(Y, Mv, F1);
    k_transpose<<<dim3(128, 64), dim3(16, 16), 0, stream>>>(F1, F1T, 2048, 4096);
    k_pass2<<<4096, 256, 0, stream>>>(F1T, GT);
    k_transpose<<<dim3(23, 128), dim3(16, 16), 0, stream>>>(GT, G, 4096, 728);
    k_pass3<<<728, 256, 0, stream>>>(G, out, partials);
    k_reduce<<<1, 256, 0, stream>>>(partials, total);
    int n = out_size;
    k_norm<<<(n + 255) / 256, 256, 0, stream>>>(out, total, n);
}

// Round 8
// 145.997 us; speedup vs baseline: 1.0397x; 1.0044x over previous
//
#include <hip/hip_runtime.h>
#include <math.h>

// ---------------- constants (replicate reference fp32 op order) -------------
constexpr double dPI     = 3.14159265358979323846;
constexpr double dLAMBDA = 5.32e-7;
constexpr double dK      = 2.0 * dPI / dLAMBDA;
constexpr double dD1     = 0.05;
constexpr double dD2     = 0.05;
constexpr double dFOCAL  = dD1 * dD2 / (dD1 + dD2);      // 0.025

constexpr float C1F         = (float)(dK / (2.0 * dD1)); // input_phase coeff
constexpr float KFF         = (float)dK;
constexpr float TWO_FOCAL_F = (float)(2.0 * dFOCAL);     // 0.05
constexpr float TPF         = (float)(2.0 * dPI);
constexpr float INV_TPF     = (float)(1.0 / (2.0 * dPI));
constexpr float TPH         = (float)(2.0 * dPI);                     // 2pi hi
constexpr float TPL         = (float)(2.0 * dPI - (double)TPH);       // 2pi lo
constexpr float SENSOR_DF   = (float)(4096.0 * 2e-6);    // 8.192e-3
constexpr float ILAM2F      = (float)((1.0 / dLAMBDA) * (1.0 / dLAMBDA));
constexpr float D2F         = (float)dD2;
constexpr float PITCHF      = 2e-6f;
constexpr float SCALE       = 1.0f / 16777216.0f;        // 2^-24 = 1/(4096*4096)

// tridiag(1,4,1) inverse kernel constants
constexpr float TRI_R = -0.2679491924311227f;            // -2+sqrt(3)
constexpr float TRI_C = 0.2886751345948129f;             // 1/(2*sqrt(3))

// ---------------- packed complex type ----------------
typedef float v2f __attribute__((ext_vector_type(2)));

__device__ __forceinline__ v2f mkv(float a, float b){ v2f r; r.x=a; r.y=b; return r; }
__device__ __forceinline__ v2f cmul(v2f a, v2f b){
    float p  = a.y * b.y;
    float re = fmaf(a.x, b.x, -p);
    float q  = a.y * b.x;
    float im = fmaf(a.x, b.y,  q);
    return mkv(re, im);
}
__device__ __forceinline__ v2f cmulc(v2f a, v2f b){    // a * conj(b)
    float p  = a.y * b.y;
    float re = fmaf(a.x, b.x,  p);
    float q  = a.x * b.y;
    float im = fmaf(a.y, b.x, -q);
    return mkv(re, im);
}

__device__ __forceinline__ int digitrev12(int p){
    int r = __brev((unsigned)p) >> 20;
    return ((r & 0x555) << 1) | ((r >> 1) & 0x555);
}

// ---------------- radix-4 butterflies (DIF fwd / DIT inv) ----------------
__device__ __forceinline__ void bfly_fwd(v2f& A, v2f& B, v2f& C, v2f& D,
                                         v2f w1, v2f w2, v2f w3){
    v2f t0=A+C, t1=A-C, t2=B+D, t3=B-D;
    v2f y0=t0+t2;
    v2f y1=mkv(t1.x + t3.y, t1.y - t3.x);   // t1 - i t3
    v2f y2=t0-t2;
    v2f y3=mkv(t1.x - t3.y, t1.y + t3.x);   // t1 + i t3
    A=y0; B=cmul(y1,w1); C=cmul(y2,w2); D=cmul(y3,w3);
}
__device__ __forceinline__ void bfly_fwd_nt(v2f& A, v2f& B, v2f& C, v2f& D){
    v2f t0=A+C, t1=A-C, t2=B+D, t3=B-D;
    A=t0+t2;
    v2f y1=mkv(t1.x + t3.y, t1.y - t3.x);
    v2f y2=t0-t2;
    v2f y3=mkv(t1.x - t3.y, t1.y + t3.x);
    B=y1; C=y2; D=y3;
}
__device__ __forceinline__ void bfly_inv(v2f& A, v2f& B, v2f& C, v2f& D,
                                         v2f w1, v2f w2, v2f w3){
    v2f bb=cmulc(B,w1), cc=cmulc(C,w2), dd=cmulc(D,w3);
    v2f t0=A+cc, t1=A-cc, t2=bb+dd, t3=bb-dd;
    A=t0+t2;
    B=mkv(t1.x - t3.y, t1.y + t3.x);        // t1 + i t3
    C=t0-t2;
    D=mkv(t1.x + t3.y, t1.y - t3.x);        // t1 - i t3
}
__device__ __forceinline__ void bfly_inv_nt(v2f& A, v2f& B, v2f& C, v2f& D){
    v2f t0=A+C, t1=A-C, t2=B+D, t3=B-D;
    A=t0+t2;
    B=mkv(t1.x - t3.y, t1.y + t3.x);
    C=t0-t2;
    D=mkv(t1.x + t3.y, t1.y - t3.x);
}

// ---------------- register-fused stage pairs (table twiddles) ---------------
// ownership A (strided): r[q] = x[t + 256 q]
// s1 (M=1024,L=4096, table off 0) + s2 (M=256,L=1024, off 1024)
template<bool ZAD>
__device__ __forceinline__ void front_fwd(v2f* r, int t,
        const v2f* __restrict__ tw1, const v2f* __restrict__ tw2,
        const v2f* __restrict__ tw3){
#pragma unroll
    for (int j = 0; j < 4; ++j){
        int m = t + 256*j;
        v2f w1 = tw1[m], w2 = tw2[m], w3 = tw3[m];
        v2f y0, y1, y2, y3;
        if (ZAD){
            v2f Bv = r[j+4], Cv = r[j+8];          // A = D = 0
            y0 = Cv + Bv;
            y1 = mkv(-Cv.x + Bv.y, -Cv.y - Bv.x);
            y2 = Cv - Bv;
            y3 = mkv(-Cv.x - Bv.y, -Cv.y + Bv.x);
        } else {
            v2f Av=r[j], Bv=r[j+4], Cv=r[j+8], Dv=r[j+12];
            v2f t0=Av+Cv, t1=Av-Cv, t2=Bv+Dv, t3=Bv-Dv;
            y0=t0+t2;
            y1=mkv(t1.x + t3.y, t1.y - t3.x);
            y2=t0-t2;
            y3=mkv(t1.x - t3.y, t1.y + t3.x);
        }
        r[j]=y0; r[j+4]=cmul(y1,w1); r[j+8]=cmul(y2,w2); r[j+12]=cmul(y3,w3);
    }
    v2f w1 = tw1[1024+t], w2 = tw2[1024+t], w3 = tw3[1024+t];
#pragma unroll
    for (int k = 0; k < 4; ++k)
        bfly_fwd(r[4*k], r[4*k+1], r[4*k+2], r[4*k+3], w1, w2, w3);
}
// ownership C (strided): i5 (M=256) + i6 (M=1024)
__device__ __forceinline__ void back_inv(v2f* r, int t,
        const v2f* __restrict__ tw1, const v2f* __restrict__ tw2,
        const v2f* __restrict__ tw3){
    v2f w1 = tw1[1024+t], w2 = tw2[1024+t], w3 = tw3[1024+t];
#pragma unroll
    for (int k = 0; k < 4; ++k)
        bfly_inv(r[4*k], r[4*k+1], r[4*k+2], r[4*k+3], w1, w2, w3);
#pragma unroll
    for (int j = 0; j < 4; ++j){
        int m = t + 256*j;
        bfly_inv(r[j], r[j+4], r[j+8], r[j+12], tw1[m], tw2[m], tw3[m]);
    }
}
// ownership B (mid): r[g] = x[256*(t>>4) + 16 g + (t&15)]
// s3 (M=64,L=256, off 1280) + s4 (M=16,L=64, off 1344)
__device__ __forceinline__ void mid_fwd(v2f* r, int c,
        const v2f* __restrict__ tw1, const v2f* __restrict__ tw2,
        const v2f* __restrict__ tw3){
#pragma unroll
    for (int h = 0; h < 4; ++h){
        int idx = 1280 + 16*h + c;
        bfly_fwd(r[h], r[h+4], r[h+8], r[h+12], tw1[idx], tw2[idx], tw3[idx]);
    }
    v2f w1 = tw1[1344+c], w2 = tw2[1344+c], w3 = tw3[1344+c];
#pragma unroll
    for (int j = 0; j < 4; ++j)
        bfly_fwd(r[4*j], r[4*j+1], r[4*j+2], r[4*j+3], w1, w2, w3);
}
__device__ __forceinline__ void mid_inv(v2f* r, int c,
        const v2f* __restrict__ tw1, const v2f* __restrict__ tw2,
        const v2f* __restrict__ tw3){
    v2f w1 = tw1[1344+c], w2 = tw2[1344+c], w3 = tw3[1344+c];
#pragma unroll
    for (int j = 0; j < 4; ++j)
        bfly_inv(r[4*j], r[4*j+1], r[4*j+2], r[4*j+3], w1, w2, w3);
#pragma unroll
    for (int h = 0; h < 4; ++h){
        int idx = 1280 + 16*h + c;
        bfly_inv(r[h], r[h+4], r[h+8], r[h+12], tw1[idx], tw2[idx], tw3[idx]);
    }
}
// ownership D (contig): r[g] = x[16 t + g]
// s5 (M=4,L=16, hardcoded) + s6 (M=1,L=4, trivial)
#define C16F 0.9238795325112867f
#define S16F 0.3826834323650898f
#define C8F  0.7071067811865476f
__device__ __forceinline__ void tail_fwd(v2f* r){
    const v2f W1[4] = {mkv(1,0),mkv(C16F,-S16F),mkv(C8F,-C8F),mkv(S16F,-C16F)};
    const v2f W2[4] = {mkv(1,0),mkv(C8F,-C8F),mkv(0,-1),mkv(-C8F,-C8F)};
    const v2f W3[4] = {mkv(1,0),mkv(S16F,-C16F),mkv(-C8F,-C8F),mkv(-C16F,S16F)};
    bfly_fwd_nt(r[0], r[4], r[8], r[12]);
#pragma unroll
    for (int m = 1; m < 4; ++m)
        bfly_fwd(r[m], r[m+4], r[m+8], r[m+12], W1[m], W2[m], W3[m]);
#pragma unroll
    for (int h = 0; h < 4; ++h)
        bfly_fwd_nt(r[4*h], r[4*h+1], r[4*h+2], r[4*h+3]);
}
// i1 (L=4, trivial) + i2 (L=16, conj of hardcoded)
__device__ __forceinline__ void head_inv(v2f* r){
    const v2f W1[4] = {mkv(1,0),mkv(C16F,-S16F),mkv(C8F,-C8F),mkv(S16F,-C16F)};
    const v2f W2[4] = {mkv(1,0),mkv(C8F,-C8F),mkv(0,-1),mkv(-C8F,-C8F)};
    const v2f W3[4] = {mkv(1,0),mkv(S16F,-C16F),mkv(-C8F,-C8F),mkv(-C16F,S16F)};
#pragma unroll
    for (int h = 0; h < 4; ++h)
        bfly_inv_nt(r[4*h], r[4*h+1], r[4*h+2], r[4*h+3]);
    bfly_inv_nt(r[0], r[4], r[8], r[12]);
#pragma unroll
    for (int m = 1; m < 4; ++m)
        bfly_inv(r[m], r[m+4], r[m+8], r[m+12], W1[m], W2[m], W3[m]);
}

// ---------------- LDS ownership exchanges (v2f, XOR-swizzled, 1 barrier) ----
__device__ __forceinline__ void x_strided_to_mid(v2f* r, v2f* lds, int t){
    int tsw = t ^ (t >> 4);
#pragma unroll
    for (int q = 0; q < 16; ++q) lds[256*q + tsw] = r[q];
    __syncthreads();
    int Bq = (t >> 4) * 256, c = t & 15;
#pragma unroll
    for (int g = 0; g < 16; ++g) r[g] = lds[Bq + 16*g + (c ^ g)];
}
__device__ __forceinline__ void x_mid_to_contig(v2f* r, v2f* lds, int t){
    int Bq = (t >> 4) * 256, c = t & 15;
#pragma unroll
    for (int g = 0; g < 16; ++g) lds[Bq + 16*g + (c ^ g)] = r[g];
    __syncthreads();
    int tl = t & 15, base = 16*t;
#pragma unroll
    for (int g = 0; g < 16; ++g) r[g] = lds[base + (g ^ tl)];
}
__device__ __forceinline__ void x_contig_to_mid(v2f* r, v2f* lds, int t){
    int tl = t & 15, base = 16*t;
#pragma unroll
    for (int g = 0; g < 16; ++g) lds[base + (g ^ tl)] = r[g];
    __syncthreads();
    int Bq = (t >> 4) * 256, c = t & 15;
#pragma unroll
    for (int g = 0; g < 16; ++g) r[g] = lds[Bq + 16*g + (c ^ g)];
}
__device__ __forceinline__ void x_mid_to_strided(v2f* r, v2f* lds, int t){
    int Bq = (t >> 4) * 256, c = t & 15;
#pragma unroll
    for (int g = 0; g < 16; ++g) lds[Bq + 16*g + (c ^ g)] = r[g];
    __syncthreads();
    int tsw = t ^ (t >> 4);
#pragma unroll
    for (int q = 0; q < 16; ++q) r[q] = lds[256*q + tsw];
}

// ---------------- twiddle tables: exact, double-generated -------------------
// layout: [0,1024): M=1024 L=4096 | [1024,1280): M=256 L=1024 |
//         [1280,1344): M=64 L=256 | [1344,1360): M=16 L=64
__global__ __launch_bounds__(256) void k_twiddle(v2f* __restrict__ tw1,
                                                 v2f* __restrict__ tw2,
                                                 v2f* __restrict__ tw3){
    int idx = blockIdx.x * 256 + threadIdx.x;
    if (idx >= 1360) return;
    int m, L;
    if (idx < 1024)      { m = idx;        L = 4096; }
    else if (idx < 1280) { m = idx - 1024; L = 1024; }
    else if (idx < 1344) { m = idx - 1280; L = 256;  }
    else                 { m = idx - 1344; L = 64;   }
    double ang = -2.0 * dPI * (double)m / (double)L;
    double s1, c1, s2, c2v, s3, c3;
    sincos(ang, &s1, &c1);
    sincos(2.0*ang, &s2, &c2v);
    sincos(3.0*ang, &s3, &c3);
    tw1[idx] = mkv((float)c1,  (float)s1);
    tw2[idx] = mkv((float)c2v, (float)s2);
    tw3[idx] = mkv((float)c3,  (float)s3);
}

// ---------------- spline: Y build + parallel analytic tridiag solve ---------
__global__ __launch_bounds__(256) void k_sY(const float* __restrict__ p,
                                            float* __restrict__ Y){
    int t = threadIdx.x;
#pragma unroll
    for (int q = 0; q < 8; ++q){
        int j = t + 256*q;
        Y[j] = (j < 1024) ? p[j >> 1] : 0.0f;   // repeat(param,2) ++ zeros
    }
}
// M = T^{-1} rhs, T = tridiag(1,4,1) size 2046; analytic decay kernel + image terms
__global__ __launch_bounds__(256) void k_sM(const float* __restrict__ Y,
                                            float* __restrict__ Mv){
    __shared__ float sY[328];
    int t = threadIdx.x;
    int B0 = blockIdx.x * 256;
    for (int k = t; k < 324; k += 256){
        int jg = B0 - 32 + k;
        sY[k] = (jg >= 0 && jg < 2048) ? Y[jg] : 0.0f;
    }
    __syncthreads();
    int i = B0 + t;
    if (i >= 2046) return;
    auto rhs = [&](int j) -> float {
        if (j < 0 || j >= 2046) return 0.0f;
        int l = j - B0 + 32;
        return 6.0f * (sY[l+2] - 2.0f*sY[l+1] + sY[l]);
    };
    float x = TRI_C * rhs(i);
    float wd = TRI_C;
    for (int d = 1; d <= 32; ++d){
        wd *= TRI_R;
        x += wd * (rhs(i-d) + rhs(i+d));
    }
    if (i < 48){                       // left image charge
        float cA = 0.0f, wj = TRI_C;
        for (int j = 0; j < 32; ++j){ wj *= TRI_R; cA += wj * rhs(j); }
        float rp = 1.0f;
        for (int k = 0; k <= i; ++k) rp *= TRI_R;    // r^{i+1}
        x -= cA * rp;
    }
    if (i >= 1998){                    // right image charge
        float cB = 0.0f, wj = TRI_C;
        for (int j = 0; j < 32; ++j){ wj *= TRI_R; cB += wj * rhs(2045 - j); }
        float rp = 1.0f;
        for (int k = 0; k < 2046 - i; ++k) rp *= TRI_R;  // r^{2046-i}
        x -= cB * rp;
    }
    Mv[i+1] = x;
    if (i == 0)    Mv[0]    = 0.0f;
    if (i == 2045) Mv[2047] = 0.0f;
}

// ---------------- pass 1: field build + fwd row FFT -------------------------
// output layout: F1[row][c'] with c' = 256 g + t  <->  storage pos p = 16 t + g
__global__ __launch_bounds__(256) void k_pass1(const float* __restrict__ Y,
        const float* __restrict__ Mv,
        const v2f* __restrict__ tw1, const v2f* __restrict__ tw2,
        const v2f* __restrict__ tw3, v2f* __restrict__ F1){
    __shared__ v2f lds[4096];
    int t = threadIdx.x;
    int row = blockIdx.x;                 // y = 1024 + row
    v2f r[16];
    int y = 1024 + row;
    int iy = row;
    int a = (iy < 1024) ? (1023 - iy) : (iy - 1024);
    float fy = PITCHF * (float)(y - 2048);
    float cy2 = fy * fy;
    float af = (float)a + 0.5f;
#pragma unroll
    for (int q = 4; q < 12; ++q){
        int x = t + 256*q;                // in [1024, 3072)
        int ix = x - 1024;
        int b = (ix < 1024) ? (1023 - ix) : (ix - 1024);
        float bf = (float)b + 0.5f;
        float rq = sqrtf(af*af + bf*bf);
        int ind = (int)rq; if (ind > 2046) ind = 2046;
        float tt = rq - (float)ind;
        float y0v = Y[ind], y1v = Y[ind+1];
        float m0 = Mv[ind], m1 = Mv[ind+1];
        float bb = (y1v - y0v) - (2.0f*m0 + m1) / 6.0f;
        float bias = y0v + tt*(bb + tt*(m0/2.0f + tt*(m1-m0)/6.0f));
        float fx = PITCHF * (float)(x - 2048);
        float r2 = fx*fx + cy2;
        float ip = C1F * r2;
        float lp = -((KFF * r2) / TWO_FOCAL_F);
        float sp = ip + lp + bias;
        float fv = sp * INV_TPF;                     // phase in revolutions
        float fr = fv - floorf(fv);                  // [0,1)
        float sn = __builtin_amdgcn_sinf(fr);
        float cs = __builtin_amdgcn_cosf(fr);
        r[q] = mkv(cs, sn);
    }
    front_fwd<true>(r, t, tw1, tw2, tw3);
    x_strided_to_mid(r, lds, t);
    mid_fwd(r, t & 15, tw1, tw2, tw3);
    x_mid_to_contig(r, lds, t);
    tail_fwd(r);
    size_t base = (size_t)row * 4096;
#pragma unroll
    for (int g = 0; g < 16; ++g)
        F1[base + 256*g + t] = r[g];      // coalesced per g
}

// ------- tiled complex transpose, float4-vectorized: in[H][W] -> out[W][H] --
__global__ __launch_bounds__(256) void k_transpose(const v2f* __restrict__ in,
                                                   v2f* __restrict__ out,
                                                   int H, int W){
    __shared__ v2f tile[32][33];
    int bx = blockIdx.x * 32, by = blockIdx.y * 32;
    int tx = threadIdx.x, ty = threadIdx.y;   // (16,16)
#pragma unroll
    for (int k = 0; k < 32; k += 16){
        int rr = by + ty + k, cc = bx + 2*tx;
        if (rr < H && cc < W){
            float4 v = *(const float4*)&in[(size_t)rr * W + cc];
            tile[ty + k][2*tx]     = mkv(v.x, v.y);
            tile[ty + k][2*tx + 1] = mkv(v.z, v.w);
        }
    }
    __syncthreads();
#pragma unroll
    for (int k = 0; k < 32; k += 16){
        int rr = bx + ty + k, cc = by + 2*tx;
        if (rr < W && cc < H){
            v2f a = tile[2*tx][ty + k];
            v2f b = tile[2*tx + 1][ty + k];
            float4 v = make_float4(a.x, a.y, b.x, b.y);
            *(float4*)&out[(size_t)rr * H + cc] = v;
        }
    }
}

// ---------------- pass 2: col fwd FFT + H + col inv FFT, crop ---------------
__global__ __launch_bounds__(256) void k_pass2(const v2f* __restrict__ F1T,
        const v2f* __restrict__ tw1, const v2f* __restrict__ tw2,
        const v2f* __restrict__ tw3, v2f* __restrict__ GT){
    __shared__ v2f lds[4096];
    int t = threadIdx.x;
    int cp = blockIdx.x;                  // c' column index
    v2f r[16];
    size_t base = (size_t)cp * 2048;
#pragma unroll
    for (int q = 4; q < 12; ++q)
        r[q] = F1T[base + t + 256*(q-4)]; // y = t + 256 q, nonzero half
    front_fwd<true>(r, t, tw1, tw2, tw3);
    x_strided_to_mid(r, lds, t);
    mid_fwd(r, t & 15, tw1, tw2, tw3);
    x_mid_to_contig(r, lds, t);
    tail_fwd(r);
    // ---- H multiply in digit-reversed frequency domain (incl. 1/N^2) ----
    int pcol = ((cp & 255) << 4) | (cp >> 8);
    int kx = digitrev12(pcol);
    int kxs = (kx + 2048) & 4095;
    float fxv = ((float)(kxs + 1) - 2048.0f) / SENSOR_DF;
    float fx2 = fxv * fxv;
    int rt = __brev((unsigned)t) >> 24;
    rt = ((rt & 0x55) << 1) | ((rt >> 1) & 0x55);   // 4-digit base-4 reversal of t
#pragma unroll
    for (int g = 0; g < 16; ++g){
        const int rg = ((g & 3) << 2) | (g >> 2);
        int ky = rg * 256 + rt;                      // digitrev12(16 t + g)
        int kys = (ky + 2048) & 4095;
        float fyv = ((float)(kys + 1) - 2048.0f) / SENSOR_DF;
        float arg = ILAM2F - fx2 - fyv*fyv;
        arg = fmaxf(arg, 0.0f);
        float w1v = sqrtf(arg);
        float Hp = (TPF * w1v) * D2F;                // exact ref fp32 value
        // fp32 Cody-Waite mod-2pi (error ~1e-7 rad), then HW trig on revs
        float v  = Hp * INV_TPF;
        float nn = rintf(v);
        float rr = fmaf(nn, -TPH, Hp);
        rr       = fmaf(nn, -TPL, rr);
        float rev = rr * INV_TPF;                    // in [-0.5, 0.5]
        float sn = __builtin_amdgcn_sinf(rev);
        float cs = __builtin_amdgcn_cosf(rev);
        r[g] = cmul(r[g], mkv(cs * SCALE, sn * SCALE));
    }
    head_inv(r);
    x_contig_to_mid(r, lds, t);
    mid_inv(r, t & 15, tw1, tw2, tw3);
    x_mid_to_strided(r, lds, t);
    back_inv(r, t, tw1, tw2, tw3);
    size_t ob = (size_t)cp * 728;
#pragma unroll
    for (int q = 6; q <= 9; ++q){
        int idx = t + 256*q - 1685;       // crop y in [1685, 2413)
        if (idx >= 0 && idx < 728) GT[ob + idx] = r[q];
    }
}

// ---------------- pass 3: inv row FFT on crop rows, |.|^2 -------------------
__global__ __launch_bounds__(256) void k_pass3(const v2f* __restrict__ G,
        float* __restrict__ out, float* __restrict__ partials,
        const v2f* __restrict__ tw1, const v2f* __restrict__ tw2,
        const v2f* __restrict__ tw3){
    __shared__ v2f lds[4096];
    int t = threadIdx.x;
    int row = blockIdx.x;
    v2f r[16];
    size_t base = (size_t)row * 4096;
#pragma unroll
    for (int g = 0; g < 16; ++g)
        r[g] = G[base + 256*g + t];       // c' = 256 g + t <-> p = 16 t + g
    head_inv(r);
    x_contig_to_mid(r, lds, t);
    mid_inv(r, t & 15, tw1, tw2, tw3);
    x_mid_to_strided(r, lds, t);
    back_inv(r, t, tw1, tw2, tw3);
    float lsum = 0.0f;
#pragma unroll
    for (int q = 6; q <= 9; ++q){
        int idx = t + 256*q - 1685;
        if (idx >= 0 && idx < 728){
            v2f v = r[q];
            float I = v.x*v.x + v.y*v.y;
            out[(size_t)row * 728 + idx] = I;
            lsum += I;
        }
    }
    __syncthreads();                       // done reading lds as v2f
    float* red = (float*)lds;
    red[t] = lsum;
    __syncthreads();
    for (int k2 = 128; k2 > 0; k2 >>= 1){
        if (t < k2) red[t] += red[t + k2];
        __syncthreads();
    }
    if (t == 0) partials[row] = red[0];
}

// ---------------- deterministic final reduction + normalize -----------------
__global__ __launch_bounds__(256) void k_reduce(const float* __restrict__ partials,
                                                float* __restrict__ total){
    __shared__ float red[256];
    int t = threadIdx.x;
    float s = 0.0f;
    for (int i = t; i < 728; i += 256) s += partials[i];
    red[t] = s;
    __syncthreads();
    for (int k = 128; k > 0; k >>= 1){
        if (t < k) red[t] += red[t + k];
        __syncthreads();
    }
    if (t == 0) *total = red[0];
}

__global__ __launch_bounds__(256) void k_norm(float* __restrict__ out,
                                              const float* __restrict__ total,
                                              int n){
    int i = blockIdx.x * 256 + threadIdx.x;
    if (i < n) out[i] = out[i] / (*total);
}

// ---------------- launch ----------------
extern "C" void kernel_launch(void* const* d_in, const int* in_sizes, int n_in,
                              void* d_out, int out_size, void* d_ws, size_t ws_size,
                              hipStream_t stream) {
    const float* p   = (const float*)d_in[0];
    float*       out = (float*)d_out;
    char*        ws  = (char*)d_ws;

    float* Y        = (float*)(ws + 0);            // 2048 f
    float* Mv       = (float*)(ws + 8192);         // 2048 f
    float* partials = (float*)(ws + 16384);        // 728 f
    float* total    = (float*)(ws + 20480);
    v2f*   tw1      = (v2f*)(ws + 24576);          // 1360 c
    v2f*   tw2      = (v2f*)(ws + 40960);
    v2f*   tw3      = (v2f*)(ws + 57344);

    const size_t BIG = (size_t)64 * 1024 * 1024;
    v2f* F1  = (v2f*)(ws + (1 << 20));             // [2048][4096]
    v2f* F1T = (v2f*)(ws + (1 << 20) + BIG);       // [4096][2048]
    v2f* GT  = F1;                                  // reuse: [4096][728]
    v2f* G   = F1T;                                 // reuse: [728][4096]

    k_sY<<<1, 256, 0, stream>>>(p, Y);
    k_sM<<<8, 256, 0, stream>>>(Y, Mv);
    k_twiddle<<<6, 256, 0, stream>>>(tw1, tw2, tw3);
    k_pass1<<<2048, 256, 0, stream>>>(Y, Mv, tw1, tw2, tw3, F1);
    k_transpose<<<dim3(128, 64), dim3(16, 16), 0, stream>>>(F1, F1T, 2048, 4096);
    k_pass2<<<4096, 256, 0, stream>>>(F1T, tw1, tw2, tw3, GT);
    k_transpose<<<dim3(23, 128), dim3(16, 16), 0, stream>>>(GT, G, 4096, 728);
    k_pass3<<<728, 256, 0, stream>>>(G, out, partials, tw1, tw2, tw3);
    k_reduce<<<1, 256, 0, stream>>>(partials, total);
    int n = out_size;
    k_norm<<<(n + 255) / 256, 256, 0, stream>>>(out, total, n);
}

// Round 9
// 125.376 us; speedup vs baseline: 1.2107x; 1.1645x over previous
//
#include <hip/hip_runtime.h>
#include <math.h>

// ---------------- constants (replicate reference fp32 op order) -------------
constexpr double dPI     = 3.14159265358979323846;
constexpr double dLAMBDA = 5.32e-7;
constexpr double dK      = 2.0 * dPI / dLAMBDA;
constexpr double dD1     = 0.05;
constexpr double dD2     = 0.05;
constexpr double dFOCAL  = dD1 * dD2 / (dD1 + dD2);      // 0.025

constexpr float C1F         = (float)(dK / (2.0 * dD1)); // input_phase coeff
constexpr float KFF         = (float)dK;
constexpr float TWO_FOCAL_F = (float)(2.0 * dFOCAL);     // 0.05
constexpr float TPF         = (float)(2.0 * dPI);
constexpr float INV_TPF     = (float)(1.0 / (2.0 * dPI));
constexpr float TPH         = (float)(2.0 * dPI);                     // 2pi hi
constexpr float TPL         = (float)(2.0 * dPI - (double)TPH);       // 2pi lo
constexpr float SENSOR_DF   = (float)(4096.0 * 2e-6);    // 8.192e-3
constexpr float ILAM2F      = (float)((1.0 / dLAMBDA) * (1.0 / dLAMBDA));
constexpr float D2F         = (float)dD2;
constexpr float PITCHF      = 2e-6f;
constexpr float SCALE       = 1.0f / 16777216.0f;        // 2^-24 = 1/(4096*4096)

// tridiag(1,4,1) inverse kernel constants
constexpr float TRI_R = -0.2679491924311227f;            // -2+sqrt(3)
constexpr float TRI_C = 0.2886751345948129f;             // 1/(2*sqrt(3))

// ---------------- packed complex types ----------------
typedef float    v2f __attribute__((ext_vector_type(2)));
typedef _Float16 h2f __attribute__((ext_vector_type(2)));

__device__ __forceinline__ v2f mkv(float a, float b){ v2f r; r.x=a; r.y=b; return r; }
__device__ __forceinline__ h2f toh(v2f v){ h2f h; h.x=(_Float16)v.x; h.y=(_Float16)v.y; return h; }
__device__ __forceinline__ v2f tof(h2f h){ return mkv((float)h.x, (float)h.y); }

__device__ __forceinline__ v2f cmul(v2f a, v2f b){
    float p  = a.y * b.y;
    float re = fmaf(a.x, b.x, -p);
    float q  = a.y * b.x;
    float im = fmaf(a.x, b.y,  q);
    return mkv(re, im);
}
__device__ __forceinline__ v2f cmulc(v2f a, v2f b){    // a * conj(b)
    float p  = a.y * b.y;
    float re = fmaf(a.x, b.x,  p);
    float q  = a.x * b.y;
    float im = fmaf(a.y, b.x, -q);
    return mkv(re, im);
}

__device__ __forceinline__ int digitrev12(int p){
    int r = __brev((unsigned)p) >> 20;
    return ((r & 0x555) << 1) | ((r >> 1) & 0x555);
}

// ---------------- radix-4 butterflies (DIF fwd / DIT inv) ----------------
__device__ __forceinline__ void bfly_fwd(v2f& A, v2f& B, v2f& C, v2f& D,
                                         v2f w1, v2f w2, v2f w3){
    v2f t0=A+C, t1=A-C, t2=B+D, t3=B-D;
    v2f y0=t0+t2;
    v2f y1=mkv(t1.x + t3.y, t1.y - t3.x);   // t1 - i t3
    v2f y2=t0-t2;
    v2f y3=mkv(t1.x - t3.y, t1.y + t3.x);   // t1 + i t3
    A=y0; B=cmul(y1,w1); C=cmul(y2,w2); D=cmul(y3,w3);
}
__device__ __forceinline__ void bfly_fwd_nt(v2f& A, v2f& B, v2f& C, v2f& D){
    v2f t0=A+C, t1=A-C, t2=B+D, t3=B-D;
    A=t0+t2;
    v2f y1=mkv(t1.x + t3.y, t1.y - t3.x);
    v2f y2=t0-t2;
    v2f y3=mkv(t1.x - t3.y, t1.y + t3.x);
    B=y1; C=y2; D=y3;
}
__device__ __forceinline__ void bfly_inv(v2f& A, v2f& B, v2f& C, v2f& D,
                                         v2f w1, v2f w2, v2f w3){
    v2f bb=cmulc(B,w1), cc=cmulc(C,w2), dd=cmulc(D,w3);
    v2f t0=A+cc, t1=A-cc, t2=bb+dd, t3=bb-dd;
    A=t0+t2;
    B=mkv(t1.x - t3.y, t1.y + t3.x);        // t1 + i t3
    C=t0-t2;
    D=mkv(t1.x + t3.y, t1.y - t3.x);        // t1 - i t3
}
__device__ __forceinline__ void bfly_inv_nt(v2f& A, v2f& B, v2f& C, v2f& D){
    v2f t0=A+C, t1=A-C, t2=B+D, t3=B-D;
    A=t0+t2;
    B=mkv(t1.x - t3.y, t1.y + t3.x);
    C=t0-t2;
    D=mkv(t1.x + t3.y, t1.y - t3.x);
}

// ---------------- register-fused stage pairs (table twiddles) ---------------
// ownership A (strided): r[q] = x[t + 256 q]
template<bool ZAD>
__device__ __forceinline__ void front_fwd(v2f* r, int t,
        const v2f* __restrict__ tw1, const v2f* __restrict__ tw2,
        const v2f* __restrict__ tw3){
#pragma unroll
    for (int j = 0; j < 4; ++j){
        int m = t + 256*j;
        v2f w1 = tw1[m], w2 = tw2[m], w3 = tw3[m];
        v2f y0, y1, y2, y3;
        if (ZAD){
            v2f Bv = r[j+4], Cv = r[j+8];          // A = D = 0
            y0 = Cv + Bv;
            y1 = mkv(-Cv.x + Bv.y, -Cv.y - Bv.x);
            y2 = Cv - Bv;
            y3 = mkv(-Cv.x - Bv.y, -Cv.y + Bv.x);
        } else {
            v2f Av=r[j], Bv=r[j+4], Cv=r[j+8], Dv=r[j+12];
            v2f t0=Av+Cv, t1=Av-Cv, t2=Bv+Dv, t3=Bv-Dv;
            y0=t0+t2;
            y1=mkv(t1.x + t3.y, t1.y - t3.x);
            y2=t0-t2;
            y3=mkv(t1.x - t3.y, t1.y + t3.x);
        }
        r[j]=y0; r[j+4]=cmul(y1,w1); r[j+8]=cmul(y2,w2); r[j+12]=cmul(y3,w3);
    }
    v2f w1 = tw1[1024+t], w2 = tw2[1024+t], w3 = tw3[1024+t];
#pragma unroll
    for (int k = 0; k < 4; ++k)
        bfly_fwd(r[4*k], r[4*k+1], r[4*k+2], r[4*k+3], w1, w2, w3);
}
// ownership C (strided): i5 (M=256) full + i6 (M=1024) pruned to crop outputs
// needed positions p = t+256q, q in {6,7,8,9}: q6=j2/s1, q7=j3/s1, q8=j0/s2, q9=j1/s2
__device__ __forceinline__ void back_inv_crop(v2f* r, int t,
        const v2f* __restrict__ tw1, const v2f* __restrict__ tw2,
        const v2f* __restrict__ tw3,
        v2f& o6, v2f& o7, v2f& o8, v2f& o9){
    v2f w1 = tw1[1024+t], w2 = tw2[1024+t], w3 = tw3[1024+t];
#pragma unroll
    for (int k = 0; k < 4; ++k)
        bfly_inv(r[4*k], r[4*k+1], r[4*k+2], r[4*k+3], w1, w2, w3);
    {   // j=0 -> slot2 -> q8
        v2f u1=tw1[t], u2=tw2[t], u3=tw3[t];
        v2f bb=cmulc(r[4],u1), cc=cmulc(r[8],u2), dd=cmulc(r[12],u3);
        o8 = (r[0]+cc) - (bb+dd);
    }
    {   // j=1 -> slot2 -> q9
        v2f u1=tw1[t+256], u2=tw2[t+256], u3=tw3[t+256];
        v2f bb=cmulc(r[5],u1), cc=cmulc(r[9],u2), dd=cmulc(r[13],u3);
        o9 = (r[1]+cc) - (bb+dd);
    }
    {   // j=2 -> slot1 -> q6
        v2f u1=tw1[t+512], u2=tw2[t+512], u3=tw3[t+512];
        v2f bb=cmulc(r[6],u1), cc=cmulc(r[10],u2), dd=cmulc(r[14],u3);
        v2f t1=r[2]-cc, t3=bb-dd;
        o6 = mkv(t1.x - t3.y, t1.y + t3.x);
    }
    {   // j=3 -> slot1 -> q7
        v2f u1=tw1[t+768], u2=tw2[t+768], u3=tw3[t+768];
        v2f bb=cmulc(r[7],u1), cc=cmulc(r[11],u2), dd=cmulc(r[15],u3);
        v2f t1=r[3]-cc, t3=bb-dd;
        o7 = mkv(t1.x - t3.y, t1.y + t3.x);
    }
}
// ownership B (mid): r[g] = x[256*(t>>4) + 16 g + (t&15)]
__device__ __forceinline__ void mid_fwd(v2f* r, int c,
        const v2f* __restrict__ tw1, const v2f* __restrict__ tw2,
        const v2f* __restrict__ tw3){
#pragma unroll
    for (int h = 0; h < 4; ++h){
        int idx = 1280 + 16*h + c;
        bfly_fwd(r[h], r[h+4], r[h+8], r[h+12], tw1[idx], tw2[idx], tw3[idx]);
    }
    v2f w1 = tw1[1344+c], w2 = tw2[1344+c], w3 = tw3[1344+c];
#pragma unroll
    for (int j = 0; j < 4; ++j)
        bfly_fwd(r[4*j], r[4*j+1], r[4*j+2], r[4*j+3], w1, w2, w3);
}
__device__ __forceinline__ void mid_inv(v2f* r, int c,
        const v2f* __restrict__ tw1, const v2f* __restrict__ tw2,
        const v2f* __restrict__ tw3){
    v2f w1 = tw1[1344+c], w2 = tw2[1344+c], w3 = tw3[1344+c];
#pragma unroll
    for (int j = 0; j < 4; ++j)
        bfly_inv(r[4*j], r[4*j+1], r[4*j+2], r[4*j+3], w1, w2, w3);
#pragma unroll
    for (int h = 0; h < 4; ++h){
        int idx = 1280 + 16*h + c;
        bfly_inv(r[h], r[h+4], r[h+8], r[h+12], tw1[idx], tw2[idx], tw3[idx]);
    }
}
// ownership D (contig): r[g] = x[16 t + g]
#define C16F 0.9238795325112867f
#define S16F 0.3826834323650898f
#define C8F  0.7071067811865476f
__device__ __forceinline__ void tail_fwd(v2f* r){
    const v2f W1[4] = {mkv(1,0),mkv(C16F,-S16F),mkv(C8F,-C8F),mkv(S16F,-C16F)};
    const v2f W2[4] = {mkv(1,0),mkv(C8F,-C8F),mkv(0,-1),mkv(-C8F,-C8F)};
    const v2f W3[4] = {mkv(1,0),mkv(S16F,-C16F),mkv(-C8F,-C8F),mkv(-C16F,S16F)};
    bfly_fwd_nt(r[0], r[4], r[8], r[12]);
#pragma unroll
    for (int m = 1; m < 4; ++m)
        bfly_fwd(r[m], r[m+4], r[m+8], r[m+12], W1[m], W2[m], W3[m]);
#pragma unroll
    for (int h = 0; h < 4; ++h)
        bfly_fwd_nt(r[4*h], r[4*h+1], r[4*h+2], r[4*h+3]);
}
__device__ __forceinline__ void head_inv(v2f* r){
    const v2f W1[4] = {mkv(1,0),mkv(C16F,-S16F),mkv(C8F,-C8F),mkv(S16F,-C16F)};
    const v2f W2[4] = {mkv(1,0),mkv(C8F,-C8F),mkv(0,-1),mkv(-C8F,-C8F)};
    const v2f W3[4] = {mkv(1,0),mkv(S16F,-C16F),mkv(-C8F,-C8F),mkv(-C16F,S16F)};
#pragma unroll
    for (int h = 0; h < 4; ++h)
        bfly_inv_nt(r[4*h], r[4*h+1], r[4*h+2], r[4*h+3]);
    bfly_inv_nt(r[0], r[4], r[8], r[12]);
#pragma unroll
    for (int m = 1; m < 4; ++m)
        bfly_inv(r[m], r[m+4], r[m+8], r[m+12], W1[m], W2[m], W3[m]);
}

// ---------------- LDS ownership exchanges (v2f, XOR-swizzled, 1 barrier) ----
__device__ __forceinline__ void x_strided_to_mid(v2f* r, v2f* lds, int t){
    int tsw = t ^ (t >> 4);
#pragma unroll
    for (int q = 0; q < 16; ++q) lds[256*q + tsw] = r[q];
    __syncthreads();
    int Bq = (t >> 4) * 256, c = t & 15;
#pragma unroll
    for (int g = 0; g < 16; ++g) r[g] = lds[Bq + 16*g + (c ^ g)];
}
__device__ __forceinline__ void x_mid_to_contig(v2f* r, v2f* lds, int t){
    int Bq = (t >> 4) * 256, c = t & 15;
#pragma unroll
    for (int g = 0; g < 16; ++g) lds[Bq + 16*g + (c ^ g)] = r[g];
    __syncthreads();
    int tl = t & 15, base = 16*t;
#pragma unroll
    for (int g = 0; g < 16; ++g) r[g] = lds[base + (g ^ tl)];
}
__device__ __forceinline__ void x_contig_to_mid(v2f* r, v2f* lds, int t){
    int tl = t & 15, base = 16*t;
#pragma unroll
    for (int g = 0; g < 16; ++g) lds[base + (g ^ tl)] = r[g];
    __syncthreads();
    int Bq = (t >> 4) * 256, c = t & 15;
#pragma unroll
    for (int g = 0; g < 16; ++g) r[g] = lds[Bq + 16*g + (c ^ g)];
}
__device__ __forceinline__ void x_mid_to_strided(v2f* r, v2f* lds, int t){
    int Bq = (t >> 4) * 256, c = t & 15;
#pragma unroll
    for (int g = 0; g < 16; ++g) lds[Bq + 16*g + (c ^ g)] = r[g];
    __syncthreads();
    int tsw = t ^ (t >> 4);
#pragma unroll
    for (int q = 0; q < 16; ++q) r[q] = lds[256*q + tsw];
}

// ---------------- twiddle tables: exact, double-generated -------------------
__global__ __launch_bounds__(256) void k_twiddle(v2f* __restrict__ tw1,
                                                 v2f* __restrict__ tw2,
                                                 v2f* __restrict__ tw3){
    int idx = blockIdx.x * 256 + threadIdx.x;
    if (idx >= 1360) return;
    int m, L;
    if (idx < 1024)      { m = idx;        L = 4096; }
    else if (idx < 1280) { m = idx - 1024; L = 1024; }
    else if (idx < 1344) { m = idx - 1280; L = 256;  }
    else                 { m = idx - 1344; L = 64;   }
    double ang = -2.0 * dPI * (double)m / (double)L;
    double s1, c1, s2, c2v, s3, c3;
    sincos(ang, &s1, &c1);
    sincos(2.0*ang, &s2, &c2v);
    sincos(3.0*ang, &s3, &c3);
    tw1[idx] = mkv((float)c1,  (float)s1);
    tw2[idx] = mkv((float)c2v, (float)s2);
    tw3[idx] = mkv((float)c3,  (float)s3);
}

// ---------------- spline: Y build + parallel analytic tridiag solve ---------
__global__ __launch_bounds__(256) void k_sY(const float* __restrict__ p,
                                            float* __restrict__ Y){
    int t = threadIdx.x;
#pragma unroll
    for (int q = 0; q < 8; ++q){
        int j = t + 256*q;
        Y[j] = (j < 1024) ? p[j >> 1] : 0.0f;   // repeat(param,2) ++ zeros
    }
}
__global__ __launch_bounds__(256) void k_sM(const float* __restrict__ Y,
                                            float* __restrict__ Mv){
    __shared__ float sY[328];
    int t = threadIdx.x;
    int B0 = blockIdx.x * 256;
    for (int k = t; k < 324; k += 256){
        int jg = B0 - 32 + k;
        sY[k] = (jg >= 0 && jg < 2048) ? Y[jg] : 0.0f;
    }
    __syncthreads();
    int i = B0 + t;
    if (i >= 2046) return;
    auto rhs = [&](int j) -> float {
        if (j < 0 || j >= 2046) return 0.0f;
        int l = j - B0 + 32;
        return 6.0f * (sY[l+2] - 2.0f*sY[l+1] + sY[l]);
    };
    float x = TRI_C * rhs(i);
    float wd = TRI_C;
    for (int d = 1; d <= 32; ++d){
        wd *= TRI_R;
        x += wd * (rhs(i-d) + rhs(i+d));
    }
    if (i < 48){
        float cA = 0.0f, wj = TRI_C;
        for (int j = 0; j < 32; ++j){ wj *= TRI_R; cA += wj * rhs(j); }
        float rp = 1.0f;
        for (int k = 0; k <= i; ++k) rp *= TRI_R;
        x -= cA * rp;
    }
    if (i >= 1998){
        float cB = 0.0f, wj = TRI_C;
        for (int j = 0; j < 32; ++j){ wj *= TRI_R; cB += wj * rhs(2045 - j); }
        float rp = 1.0f;
        for (int k = 0; k < 2046 - i; ++k) rp *= TRI_R;
        x -= cB * rp;
    }
    Mv[i+1] = x;
    if (i == 0)    Mv[0]    = 0.0f;
    if (i == 2045) Mv[2047] = 0.0f;
}

// ---------------- pass 1: field build + fwd row FFT (fp16 out) --------------
__global__ __launch_bounds__(256) void k_pass1(const float* __restrict__ Y,
        const float* __restrict__ Mv,
        const v2f* __restrict__ tw1, const v2f* __restrict__ tw2,
        const v2f* __restrict__ tw3, h2f* __restrict__ F1){
    __shared__ v2f lds[4096];
    int t = threadIdx.x;
    int row = blockIdx.x;                 // y = 1024 + row
    v2f r[16];
    int y = 1024 + row;
    int iy = row;
    int a = (iy < 1024) ? (1023 - iy) : (iy - 1024);
    float fy = PITCHF * (float)(y - 2048);
    float cy2 = fy * fy;
    float af = (float)a + 0.5f;
#pragma unroll
    for (int q = 4; q < 12; ++q){
        int x = t + 256*q;                // in [1024, 3072)
        int ix = x - 1024;
        int b = (ix < 1024) ? (1023 - ix) : (ix - 1024);
        float bf = (float)b + 0.5f;
        float rq = sqrtf(af*af + bf*bf);
        int ind = (int)rq; if (ind > 2046) ind = 2046;
        float tt = rq - (float)ind;
        float y0v = Y[ind], y1v = Y[ind+1];
        float m0 = Mv[ind], m1 = Mv[ind+1];
        float bb = (y1v - y0v) - (2.0f*m0 + m1) / 6.0f;
        float bias = y0v + tt*(bb + tt*(m0/2.0f + tt*(m1-m0)/6.0f));
        float fx = PITCHF * (float)(x - 2048);
        float r2 = fx*fx + cy2;
        float ip = C1F * r2;
        float lp = -((KFF * r2) / TWO_FOCAL_F);
        float sp = ip + lp + bias;
        float fv = sp * INV_TPF;                     // phase in revolutions
        float fr = fv - floorf(fv);                  // [0,1)
        float sn = __builtin_amdgcn_sinf(fr);
        float cs = __builtin_amdgcn_cosf(fr);
        r[q] = mkv(cs, sn);
    }
    front_fwd<true>(r, t, tw1, tw2, tw3);
    x_strided_to_mid(r, lds, t);
    mid_fwd(r, t & 15, tw1, tw2, tw3);
    x_mid_to_contig(r, lds, t);
    tail_fwd(r);
    size_t base = (size_t)row * 4096;
#pragma unroll
    for (int g = 0; g < 16; ++g)
        F1[base + 256*g + t] = toh(r[g]);  // coalesced per g
}

// ------- tiled 4-byte transpose (h2f as uint), uint2-vectorized -------------
__global__ __launch_bounds__(256) void k_transpose_h(const unsigned* __restrict__ in,
                                                     unsigned* __restrict__ out,
                                                     int H, int W){
    __shared__ unsigned tile[32][33];
    int bx = blockIdx.x * 32, by = blockIdx.y * 32;
    int tx = threadIdx.x, ty = threadIdx.y;   // (16,16)
#pragma unroll
    for (int k = 0; k < 32; k += 16){
        int rr = by + ty + k, cc = bx + 2*tx;
        if (rr < H && cc < W){
            uint2 v = *(const uint2*)&in[(size_t)rr * W + cc];
            tile[ty + k][2*tx]     = v.x;
            tile[ty + k][2*tx + 1] = v.y;
        }
    }
    __syncthreads();
#pragma unroll
    for (int k = 0; k < 32; k += 16){
        int rr = bx + ty + k, cc = by + 2*tx;
        if (rr < W && cc < H){
            uint2 v = make_uint2(tile[2*tx][ty + k], tile[2*tx + 1][ty + k]);
            *(uint2*)&out[(size_t)rr * H + cc] = v;
        }
    }
}

// ---------------- pass 2: col fwd FFT + H + col inv FFT, crop ---------------
__global__ __launch_bounds__(256) void k_pass2(const h2f* __restrict__ F1T,
        const v2f* __restrict__ tw1, const v2f* __restrict__ tw2,
        const v2f* __restrict__ tw3, h2f* __restrict__ GT){
    __shared__ v2f lds[4096];
    int t = threadIdx.x;
    int cp = blockIdx.x;                  // c' column index
    v2f r[16];
    size_t base = (size_t)cp * 2048;
#pragma unroll
    for (int q = 4; q < 12; ++q)
        r[q] = tof(F1T[base + t + 256*(q-4)]); // y = t + 256 q, nonzero half
    front_fwd<true>(r, t, tw1, tw2, tw3);
    x_strided_to_mid(r, lds, t);
    mid_fwd(r, t & 15, tw1, tw2, tw3);
    x_mid_to_contig(r, lds, t);
    tail_fwd(r);
    // ---- H multiply in digit-reversed frequency domain (incl. 1/N^2) ----
    int pcol = ((cp & 255) << 4) | (cp >> 8);
    int kx = digitrev12(pcol);
    int kxs = (kx + 2048) & 4095;
    float fxv = ((float)(kxs + 1) - 2048.0f) / SENSOR_DF;
    float fx2 = fxv * fxv;
    int rt = __brev((unsigned)t) >> 24;
    rt = ((rt & 0x55) << 1) | ((rt >> 1) & 0x55);   // 4-digit base-4 reversal of t
#pragma unroll
    for (int g = 0; g < 16; ++g){
        const int rg = ((g & 3) << 2) | (g >> 2);
        int ky = rg * 256 + rt;                      // digitrev12(16 t + g)
        int kys = (ky + 2048) & 4095;
        float fyv = ((float)(kys + 1) - 2048.0f) / SENSOR_DF;
        float arg = ILAM2F - fx2 - fyv*fyv;
        arg = fmaxf(arg, 0.0f);
        float w1v = sqrtf(arg);
        float Hp = (TPF * w1v) * D2F;                // exact ref fp32 value
        float v  = Hp * INV_TPF;
        float nn = rintf(v);
        float rr = fmaf(nn, -TPH, Hp);
        rr       = fmaf(nn, -TPL, rr);
        float rev = rr * INV_TPF;                    // in [-0.5, 0.5]
        float sn = __builtin_amdgcn_sinf(rev);
        float cs = __builtin_amdgcn_cosf(rev);
        r[g] = cmul(r[g], mkv(cs * SCALE, sn * SCALE));
    }
    head_inv(r);
    x_contig_to_mid(r, lds, t);
    mid_inv(r, t & 15, tw1, tw2, tw3);
    x_mid_to_strided(r, lds, t);
    v2f o6, o7, o8, o9;
    back_inv_crop(r, t, tw1, tw2, tw3, o6, o7, o8, o9);
    size_t ob = (size_t)cp * 728;
    // crop y in [1685, 2413): idx = t + 256q - 1685
    if (t >= 149) GT[ob + t - 149] = toh(o6);
    GT[ob + t + 107] = toh(o7);
    GT[ob + t + 363] = toh(o8);
    if (t < 109)  GT[ob + t + 619] = toh(o9);
}

// ---------------- pass 3: inv row FFT on crop rows, |.|^2 -------------------
__global__ __launch_bounds__(256) void k_pass3(const h2f* __restrict__ G,
        float* __restrict__ out, float* __restrict__ partials,
        const v2f* __restrict__ tw1, const v2f* __restrict__ tw2,
        const v2f* __restrict__ tw3){
    __shared__ v2f lds[4096];
    int t = threadIdx.x;
    int row = blockIdx.x;
    v2f r[16];
    size_t base = (size_t)row * 4096;
#pragma unroll
    for (int g = 0; g < 16; ++g)
        r[g] = tof(G[base + 256*g + t]);  // c' = 256 g + t <-> p = 16 t + g
    head_inv(r);
    x_contig_to_mid(r, lds, t);
    mid_inv(r, t & 15, tw1, tw2, tw3);
    x_mid_to_strided(r, lds, t);
    v2f o6, o7, o8, o9;
    back_inv_crop(r, t, tw1, tw2, tw3, o6, o7, o8, o9);
    float lsum = 0.0f;
    size_t ob = (size_t)row * 728;
    if (t >= 149){ float I = o6.x*o6.x + o6.y*o6.y; out[ob + t - 149] = I; lsum += I; }
    { float I = o7.x*o7.x + o7.y*o7.y; out[ob + t + 107] = I; lsum += I; }
    { float I = o8.x*o8.x + o8.y*o8.y; out[ob + t + 363] = I; lsum += I; }
    if (t < 109){ float I = o9.x*o9.x + o9.y*o9.y; out[ob + t + 619] = I; lsum += I; }
    __syncthreads();                       // all exchange reads done
    float* red = (float*)lds;
    red[t] = lsum;
    __syncthreads();
    for (int k2 = 128; k2 > 0; k2 >>= 1){
        if (t < k2) red[t] += red[t + k2];
        __syncthreads();
    }
    if (t == 0) partials[row] = red[0];
}

// ---------------- deterministic final reduction + normalize -----------------
__global__ __launch_bounds__(256) void k_reduce(const float* __restrict__ partials,
                                                float* __restrict__ total){
    __shared__ float red[256];
    int t = threadIdx.x;
    float s = 0.0f;
    for (int i = t; i < 728; i += 256) s += partials[i];
    red[t] = s;
    __syncthreads();
    for (int k = 128; k > 0; k >>= 1){
        if (t < k) red[t] += red[t + k];
        __syncthreads();
    }
    if (t == 0) *total = red[0];
}

__global__ __launch_bounds__(256) void k_norm(float* __restrict__ out,
                                              const float* __restrict__ total,
                                              int n){
    int i = blockIdx.x * 256 + threadIdx.x;
    if (i < n) out[i] = out[i] / (*total);
}

// ---------------- launch ----------------
extern "C" void kernel_launch(void* const* d_in, const int* in_sizes, int n_in,
                              void* d_out, int out_size, void* d_ws, size_t ws_size,
                              hipStream_t stream) {
    const float* p   = (const float*)d_in[0];
    float*       out = (float*)d_out;
    char*        ws  = (char*)d_ws;

    float* Y        = (float*)(ws + 0);            // 2048 f
    float* Mv       = (float*)(ws + 8192);         // 2048 f
    float* partials = (float*)(ws + 16384);        // 728 f
    float* total    = (float*)(ws + 20480);
    v2f*   tw1      = (v2f*)(ws + 24576);          // 1360 c (fp32)
    v2f*   tw2      = (v2f*)(ws + 40960);
    v2f*   tw3      = (v2f*)(ws + 57344);

    const size_t BIG = (size_t)64 * 1024 * 1024;
    h2f* F1  = (h2f*)(ws + (1 << 20));             // [2048][4096] fp16c, 32MB
    h2f* F1T = (h2f*)(ws + (1 << 20) + BIG);       // [4096][2048] fp16c
    h2f* GT  = F1;                                  // reuse: [4096][728]
    h2f* G   = F1T;                                 // reuse: [728][4096]

    k_sY<<<1, 256, 0, stream>>>(p, Y);
    k_sM<<<8, 256, 0, stream>>>(Y, Mv);
    k_twiddle<<<6, 256, 0, stream>>>(tw1, tw2, tw3);
    k_pass1<<<2048, 256, 0, stream>>>(Y, Mv, tw1, tw2, tw3, F1);
    k_transpose_h<<<dim3(128, 64), dim3(16, 16), 0, stream>>>((const unsigned*)F1, (unsigned*)F1T, 2048, 4096);
    k_pass2<<<4096, 256, 0, stream>>>(F1T, tw1, tw2, tw3, GT);
    k_transpose_h<<<dim3(23, 128), dim3(16, 16), 0, stream>>>((const unsigned*)GT, (unsigned*)G, 4096, 728);
    k_pass3<<<728, 256, 0, stream>>>(G, out, partials, tw1, tw2, tw3);
    k_reduce<<<1, 256, 0, stream>>>(partials, total);
    int n = out_size;
    k_norm<<<(n + 255) / 256, 256, 0, stream>>>(out, total, n);
}